// Round 1
// baseline (412.343 us; speedup 1.0000x reference)
//
#include <hip/hip_runtime.h>
#include <cstdint>
#include <cstring>

#define M_TOK 2048   // BT*S
#define DDIM 4096
#define CDIM 1024
#define LTOT 25

typedef __bf16 bf16_t;
typedef __attribute__((ext_vector_type(8))) __bf16 bf16x8;
typedef __attribute__((ext_vector_type(4))) float f32x4;

__device__ __forceinline__ void gload16(const void* g, void* l) {
  __builtin_amdgcn_global_load_lds(
      (const __attribute__((address_space(1))) unsigned int*)g,
      (__attribute__((address_space(3))) unsigned int*)l, 16, 0, 0);
}

// ---------------- fp32 -> bf16 convert (grid-stride, 8 elems/thread) ----------------
__global__ void cvt_bf16(const float* __restrict__ src, bf16_t* __restrict__ dst, long n) {
  long stride = (long)gridDim.x * blockDim.x;
  for (long i = (long)blockIdx.x * blockDim.x + threadIdx.x; i * 8 < n; i += stride) {
    const float4* s4 = (const float4*)(src + i * 8);
    float4 a = s4[0], b = s4[1];
    bf16_t o[8] = {(bf16_t)a.x, (bf16_t)a.y, (bf16_t)a.z, (bf16_t)a.w,
                   (bf16_t)b.x, (bf16_t)b.y, (bf16_t)b.z, (bf16_t)b.w};
    uint4 pk;
    __builtin_memcpy(&pk, o, 16);
    *(uint4*)(dst + i * 8) = pk;
  }
}

// ---------------- LayerNorm + gather + bf16 convert ----------------
// block = one (m, jl) row; j = jBase + jl ; j<7: LN(layer 24-4j), j==7: raw layer 24
__global__ __launch_bounds__(256)
void ln_convert(const float* __restrict__ af, const float* __restrict__ gamma,
                const float* __restrict__ beta, bf16_t* __restrict__ xn, int jBase)
{
  int m = blockIdx.x;
  int jl = blockIdx.y;
  int j = jBase + jl;
  int layer = (j < 7) ? (24 - 4 * j) : 24;
  const float4* row4 = (const float4*)(af + ((size_t)m * LTOT + layer) * DDIM);
  int tid = threadIdx.x;
  float4 v[4];
  float s = 0.f, ss = 0.f;
#pragma unroll
  for (int i = 0; i < 4; ++i) {
    v[i] = row4[i * 256 + tid];
    s += v[i].x + v[i].y + v[i].z + v[i].w;
    ss += v[i].x * v[i].x + v[i].y * v[i].y + v[i].z * v[i].z + v[i].w * v[i].w;
  }
  int lane = tid & 63, wv = tid >> 6;
#pragma unroll
  for (int off = 32; off; off >>= 1) { s += __shfl_xor(s, off); ss += __shfl_xor(ss, off); }
  __shared__ float red[8];
  if (lane == 0) { red[wv] = s; red[4 + wv] = ss; }
  __syncthreads();
  s = red[0] + red[1] + red[2] + red[3];
  ss = red[4] + red[5] + red[6] + red[7];
  float mu = 0.f, rs = 1.f;
  if (j < 7) {
    mu = s * (1.f / DDIM);
    float var = ss * (1.f / DDIM) - mu * mu;
    rs = rsqrtf(var + 1e-5f);
  }
  bf16_t* orow = xn + ((size_t)jl * M_TOK + m) * DDIM;
  int jw = (j < 7) ? j : 0;
  const float4* g4 = (const float4*)(gamma + (size_t)jw * DDIM);
  const float4* b4 = (const float4*)(beta + (size_t)jw * DDIM);
#pragma unroll
  for (int i = 0; i < 4; ++i) {
    float4 x = v[i];
    float4 ov;
    if (j < 7) {
      float4 g = g4[i * 256 + tid], bb = b4[i * 256 + tid];
      ov.x = (x.x - mu) * rs * g.x + bb.x;
      ov.y = (x.y - mu) * rs * g.y + bb.y;
      ov.z = (x.z - mu) * rs * g.z + bb.z;
      ov.w = (x.w - mu) * rs * g.w + bb.w;
    } else ov = x;
    bf16_t o[4] = {(bf16_t)ov.x, (bf16_t)ov.y, (bf16_t)ov.z, (bf16_t)ov.w};
    uint2 pk;
    __builtin_memcpy(&pk, o, 8);
    ((uint2*)orow)[i * 256 + tid] = pk;
  }
}

// ---------------- batched B^T GEMM: C[jg][m][n] = sum_k A[jl][m][k]*B[jl][n][k] ----------------
// m97 structure: 128x128 tile, BK=64, 4 waves (2x2), global_load_lds width 16,
// mfma_f32_16x16x32_bf16, fp32 epilogue.
// EPI=0: C slab jg; bias (input_b) added iff jg==7.
// EPI=1: C = Cout flat; adds vin[m][n] + bias[n].
template <int EPI>
__global__ __launch_bounds__(256)
void gemm_bt(const bf16_t* __restrict__ A, const bf16_t* __restrict__ B,
             float* __restrict__ Cout, const float* __restrict__ bias,
             const float* __restrict__ vin,
             int Mm, int Nn, int Kk, int jBase, int tilesPerJ, int tilesN)
{
  __shared__ bf16_t As[128 * 64];
  __shared__ bf16_t Bs[128 * 64];
  int nb = gridDim.x;
  int bid = blockIdx.x;
  if ((nb & 7) == 0) { int cpx = nb >> 3; bid = (bid & 7) * cpx + (bid >> 3); }  // XCD swizzle
  int jl = bid / tilesPerJ;
  int t = bid % tilesPerJ;
  int bm = t / tilesN, bn = t % tilesN;
  int jg = jBase + jl;
  const bf16_t* Aj = A + (size_t)jl * Mm * Kk + (size_t)bm * 128 * Kk;
  const bf16_t* Bj = B + (size_t)jl * Nn * Kk + (size_t)bn * 128 * Kk;

  int tid = threadIdx.x;
  int lane = tid & 63, wv = tid >> 6;
  int wm = wv >> 1, wn = wv & 1;

  f32x4 acc[4][4] = {};

  int srow = wv * 32 + (lane >> 3);
  int scol = (lane & 7) * 8;
  const bf16_t* Ag = Aj + (size_t)srow * Kk + scol;
  const bf16_t* Bg = Bj + (size_t)srow * Kk + scol;

  for (int kt = 0; kt < Kk; kt += 64) {
#pragma unroll
    for (int c = 0; c < 4; ++c) {
      gload16(Ag + kt + (size_t)(c * 8) * Kk, &As[(wv * 32 + c * 8) * 64]);
      gload16(Bg + kt + (size_t)(c * 8) * Kk, &Bs[(wv * 32 + c * 8) * 64]);
    }
    __syncthreads();
#pragma unroll
    for (int ks = 0; ks < 2; ++ks) {
      int ko = ks * 32 + (lane >> 4) * 8;
      bf16x8 af[4], bfr[4];
#pragma unroll
      for (int i = 0; i < 4; ++i) {
        af[i] = *(const bf16x8*)&As[(wm * 64 + i * 16 + (lane & 15)) * 64 + ko];
        bfr[i] = *(const bf16x8*)&Bs[(wn * 64 + i * 16 + (lane & 15)) * 64 + ko];
      }
#pragma unroll
      for (int i = 0; i < 4; ++i)
#pragma unroll
        for (int j2 = 0; j2 < 4; ++j2)
          acc[i][j2] = __builtin_amdgcn_mfma_f32_16x16x32_bf16(af[i], bfr[j2], acc[i][j2], 0, 0, 0);
    }
    __syncthreads();
  }

  int rowBase = bm * 128 + wm * 64 + (lane >> 4) * 4;
  int colBase = bn * 128 + wn * 64 + (lane & 15);
  float* Cj = (EPI == 0) ? (Cout + (size_t)jg * Mm * Nn) : Cout;
#pragma unroll
  for (int i = 0; i < 4; ++i) {
#pragma unroll
    for (int j2 = 0; j2 < 4; ++j2) {
      int gn = colBase + j2 * 16;
      float bv = 0.f;
      if (EPI == 0) { if (jg == 7) bv = bias[gn]; }
      else bv = bias[gn];
#pragma unroll
      for (int r = 0; r < 4; ++r) {
        int gm = rowBase + i * 16 + r;
        float v = acc[i][j2][r] + bv;
        if (EPI == 1) v += vin[(size_t)gm * Nn + gn];
        Cj[(size_t)gm * Nn + gn] = v;
      }
    }
  }
}

// ---------------- attention over 6 kv slabs, per (m, head) wave ----------------
__global__ __launch_bounds__(512)
void attn_fuse(const float* __restrict__ vo, bf16_t* __restrict__ fuse)
{
  int m = blockIdx.x;
  int h = threadIdx.x >> 6;
  int lane = threadIdx.x & 63;
  const size_t slab = (size_t)M_TOK * CDIM;
  const float* base = vo + (size_t)m * CDIM + h * 128;
  float q0 = base[lane], q1 = base[lane + 64];
  float kv0[6], kv1[6], sc[6];
#pragma unroll
  for (int k = 0; k < 6; ++k) {
    const float* kb = base + (size_t)(k + 1) * slab;
    kv0[k] = kb[lane]; kv1[k] = kb[lane + 64];
    sc[k] = q0 * kv0[k] + q1 * kv1[k];
  }
#pragma unroll
  for (int k = 0; k < 6; ++k) {
#pragma unroll
    for (int off = 32; off; off >>= 1) sc[k] += __shfl_xor(sc[k], off);
    sc[k] *= 0.03125f;  // C^-0.5
  }
  float mx = sc[0];
#pragma unroll
  for (int k = 1; k < 6; ++k) mx = fmaxf(mx, sc[k]);
  float e[6], se = 0.f;
#pragma unroll
  for (int k = 0; k < 6; ++k) { e[k] = expf(sc[k] - mx); se += e[k]; }
  float inv = 1.f / se;
  float f0 = 0.f, f1 = 0.f;
#pragma unroll
  for (int k = 0; k < 6; ++k) { float w = e[k] * inv; f0 += w * kv0[k]; f1 += w * kv1[k]; }
  bf16_t* o = fuse + (size_t)m * CDIM + h * 128;
  o[lane] = (bf16_t)f0;
  o[lane + 64] = (bf16_t)f1;
}

// ---------------- cosine per row ----------------
__global__ __launch_bounds__(256)
void cos_row(const float* __restrict__ vf, const float* __restrict__ teacher, float* __restrict__ cosv)
{
  int m = blockIdx.x;
  int tid = threadIdx.x;
  float4 a = ((const float4*)(vf + (size_t)m * CDIM))[tid];
  float4 b = ((const float4*)(teacher + (size_t)m * CDIM))[tid];
  float dot = a.x * b.x + a.y * b.y + a.z * b.z + a.w * b.w;
  float na = a.x * a.x + a.y * a.y + a.z * a.z + a.w * a.w;
  float nb = b.x * b.x + b.y * b.y + b.z * b.z + b.w * b.w;
  int lane = tid & 63, wv = tid >> 6;
#pragma unroll
  for (int off = 32; off; off >>= 1) {
    dot += __shfl_xor(dot, off); na += __shfl_xor(na, off); nb += __shfl_xor(nb, off);
  }
  __shared__ float red[12];
  if (lane == 0) { red[wv] = dot; red[4 + wv] = na; red[8 + wv] = nb; }
  __syncthreads();
  if (tid == 0) {
    float d = red[0] + red[1] + red[2] + red[3];
    float x = red[4] + red[5] + red[6] + red[7];
    float y = red[8] + red[9] + red[10] + red[11];
    float den = fmaxf(sqrtf(x), 1e-8f) * fmaxf(sqrtf(y), 1e-8f);
    cosv[m] = d / den;
  }
}

__global__ __launch_bounds__(256)
void final_reduce(const float* __restrict__ cosv, float* __restrict__ out)
{
  int tid = threadIdx.x;
  float s = 0.f;
  for (int i = tid; i < M_TOK; i += 256) s += cosv[i];
  int lane = tid & 63, wv = tid >> 6;
#pragma unroll
  for (int off = 32; off; off >>= 1) s += __shfl_xor(s, off);
  __shared__ float red[4];
  if (lane == 0) red[wv] = s;
  __syncthreads();
  if (tid == 0) out[0] = 1.f - (red[0] + red[1] + red[2] + red[3]) * (1.f / M_TOK);
}

extern "C" void kernel_launch(void* const* d_in, const int* in_sizes, int n_in,
                              void* d_out, int out_size, void* d_ws, size_t ws_size,
                              hipStream_t stream)
{
  (void)in_sizes; (void)n_in; (void)out_size;
  const float* all_features = (const float*)d_in[0];
  const float* teacher = (const float*)d_in[1];
  const float* ln_gamma = (const float*)d_in[2];
  const float* ln_beta = (const float*)d_in[3];
  const float* norm_w = (const float*)d_in[4];
  const float* input_w = (const float*)d_in[5];
  const float* input_b = (const float*)d_in[6];
  const float* output_w = (const float*)d_in[7];
  const float* output_b = (const float*)d_in[8];
  float* out = (float*)d_out;
  char* ws = (char*)d_ws;

  const size_t M = M_TOK, D = DDIM, C = CDIM;
  const size_t xnB = 8 * M * D * 2;      // 134 MB  (8 bf16 GEMM A-slabs; slab7 = raw layer24)
  const size_t wbB = 8 * C * D * 2;      // 67 MB   (norm_w[0..6] + input_w, bf16)
  const size_t owbB = C * C * 2;         // 2 MB
  const size_t voB = 8 * M * C * 4;      // 67 MB   (vo fp32; slab7 = vin)
  const size_t fuseB = M * C * 2;        // 4.2 MB
  const size_t vfB = M * C * 4;          // 8.4 MB
  const size_t cosB = M * 4;
  const size_t fastTotal = xnB + wbB + owbB + voB + fuseB + vfB + cosB;  // ~283 MB

  if (ws_size >= fastTotal) {
    bf16_t* xn = (bf16_t*)ws;
    bf16_t* wb = (bf16_t*)(ws + xnB);
    bf16_t* owb = (bf16_t*)(ws + xnB + wbB);
    float* vo = (float*)(ws + xnB + wbB + owbB);
    bf16_t* fuse = (bf16_t*)(ws + xnB + wbB + owbB + voB);
    float* vf = (float*)(ws + xnB + wbB + owbB + voB + fuseB);
    float* cosv = (float*)(ws + xnB + wbB + owbB + voB + fuseB + vfB);

    cvt_bf16<<<4096, 256, 0, stream>>>(norm_w, wb, (long)7 * C * D);
    cvt_bf16<<<2048, 256, 0, stream>>>(input_w, wb + (size_t)7 * C * D, (long)(C * D));
    cvt_bf16<<<512, 256, 0, stream>>>(output_w, owb, (long)(C * C));
    dim3 g1((unsigned)M, 8);
    ln_convert<<<g1, 256, 0, stream>>>(all_features, ln_gamma, ln_beta, xn, 0);
    gemm_bt<0><<<1024, 256, 0, stream>>>(xn, wb, vo, input_b, nullptr,
                                         (int)M, (int)C, (int)D, 0, 128, 8);
    attn_fuse<<<(unsigned)M, 512, 0, stream>>>(vo, fuse);
    gemm_bt<1><<<128, 256, 0, stream>>>(fuse, owb, vf, output_b, vo + (size_t)7 * M * C,
                                        (int)M, (int)C, (int)C, 0, 128, 8);
    cos_row<<<(unsigned)M, 256, 0, stream>>>(vf, teacher, cosv);
    final_reduce<<<1, 256, 0, stream>>>(cosv, out);
  } else {
    // SMALL-ws fallback (~107 MB): loop j, reuse one xn/wb slab.
    const size_t xn1B = M * D * 2;
    const size_t wb1B = C * D * 2;
    bf16_t* xn1 = (bf16_t*)ws;
    bf16_t* wb1 = (bf16_t*)(ws + xn1B);
    bf16_t* owb = (bf16_t*)(ws + xn1B + wb1B);
    float* vo = (float*)(ws + xn1B + wb1B + owbB);
    bf16_t* fuse = (bf16_t*)(ws + xn1B + wb1B + owbB + voB);
    float* vf = (float*)(ws + xn1B + wb1B + owbB + voB + fuseB);
    float* cosv = (float*)(ws + xn1B + wb1B + owbB + voB + fuseB + vfB);

    cvt_bf16<<<512, 256, 0, stream>>>(output_w, owb, (long)(C * C));
    for (int j = 0; j < 8; ++j) {
      const float* wsrc = (j < 7) ? (norm_w + (size_t)j * C * D) : input_w;
      cvt_bf16<<<2048, 256, 0, stream>>>(wsrc, wb1, (long)(C * D));
      dim3 g1((unsigned)M, 1);
      ln_convert<<<g1, 256, 0, stream>>>(all_features, ln_gamma, ln_beta, xn1, j);
      gemm_bt<0><<<128, 256, 0, stream>>>(xn1, wb1, vo, input_b, nullptr,
                                          (int)M, (int)C, (int)D, j, 128, 8);
    }
    attn_fuse<<<(unsigned)M, 512, 0, stream>>>(vo, fuse);
    gemm_bt<1><<<128, 256, 0, stream>>>(fuse, owb, vf, output_b, vo + (size_t)7 * M * C,
                                        (int)M, (int)C, (int)C, 0, 128, 8);
    cos_row<<<(unsigned)M, 256, 0, stream>>>(vf, teacher, cosv);
    final_reduce<<<1, 256, 0, stream>>>(cosv, out);
  }
}

// Round 3
// 316.914 us; speedup vs baseline: 1.3011x; 1.3011x over previous
//
#include <hip/hip_runtime.h>
#include <cstdint>
#include <cstring>

#define M_TOK 2048   // BT*S
#define DDIM 4096
#define CDIM 1024
#define LTOT 25

typedef __bf16 bf16_t;
typedef __attribute__((ext_vector_type(8))) __bf16 bf16x8;
typedef __attribute__((ext_vector_type(4))) float f32x4;

__device__ __forceinline__ void gload16(const void* g, void* l) {
  __builtin_amdgcn_global_load_lds(
      (const __attribute__((address_space(1))) unsigned int*)g,
      (__attribute__((address_space(3))) unsigned int*)l, 16, 0, 0);
}

// ---------------- fp32 -> bf16 convert ----------------
__global__ void cvt_bf16(const float* __restrict__ src, bf16_t* __restrict__ dst, long n) {
  long stride = (long)gridDim.x * blockDim.x;
  for (long i = (long)blockIdx.x * blockDim.x + threadIdx.x; i * 8 < n; i += stride) {
    const float4* s4 = (const float4*)(src + i * 8);
    float4 a = s4[0], b = s4[1];
    bf16_t o[8] = {(bf16_t)a.x, (bf16_t)a.y, (bf16_t)a.z, (bf16_t)a.w,
                   (bf16_t)b.x, (bf16_t)b.y, (bf16_t)b.z, (bf16_t)b.w};
    uint4 pk;
    __builtin_memcpy(&pk, o, 16);
    *(uint4*)(dst + i * 8) = pk;
  }
}

// ---------------- LayerNorm + gather + bf16 convert ----------------
__global__ __launch_bounds__(256)
void ln_convert(const float* __restrict__ af, const float* __restrict__ gamma,
                const float* __restrict__ beta, bf16_t* __restrict__ xn, int jBase)
{
  int m = blockIdx.x;
  int jl = blockIdx.y;
  int j = jBase + jl;
  int layer = (j < 7) ? (24 - 4 * j) : 24;
  const float4* row4 = (const float4*)(af + ((size_t)m * LTOT + layer) * DDIM);
  int tid = threadIdx.x;
  float4 v[4];
  float s = 0.f, ss = 0.f;
#pragma unroll
  for (int i = 0; i < 4; ++i) {
    v[i] = row4[i * 256 + tid];
    s += v[i].x + v[i].y + v[i].z + v[i].w;
    ss += v[i].x * v[i].x + v[i].y * v[i].y + v[i].z * v[i].z + v[i].w * v[i].w;
  }
  int lane = tid & 63, wv = tid >> 6;
#pragma unroll
  for (int off = 32; off; off >>= 1) { s += __shfl_xor(s, off); ss += __shfl_xor(ss, off); }
  __shared__ float red[8];
  if (lane == 0) { red[wv] = s; red[4 + wv] = ss; }
  __syncthreads();
  s = red[0] + red[1] + red[2] + red[3];
  ss = red[4] + red[5] + red[6] + red[7];
  float mu = 0.f, rs = 1.f;
  if (j < 7) {
    mu = s * (1.f / DDIM);
    float var = ss * (1.f / DDIM) - mu * mu;
    rs = rsqrtf(var + 1e-5f);
  }
  bf16_t* orow = xn + ((size_t)jl * M_TOK + m) * DDIM;
  int jw = (j < 7) ? j : 0;
  const float4* g4 = (const float4*)(gamma + (size_t)jw * DDIM);
  const float4* b4 = (const float4*)(beta + (size_t)jw * DDIM);
#pragma unroll
  for (int i = 0; i < 4; ++i) {
    float4 x = v[i];
    float4 ov;
    if (j < 7) {
      float4 g = g4[i * 256 + tid], bb = b4[i * 256 + tid];
      ov.x = (x.x - mu) * rs * g.x + bb.x;
      ov.y = (x.y - mu) * rs * g.y + bb.y;
      ov.z = (x.z - mu) * rs * g.z + bb.z;
      ov.w = (x.w - mu) * rs * g.w + bb.w;
    } else ov = x;
    bf16_t o[4] = {(bf16_t)ov.x, (bf16_t)ov.y, (bf16_t)ov.z, (bf16_t)ov.w};
    uint2 pk;
    __builtin_memcpy(&pk, o, 8);
    ((uint2*)orow)[i * 256 + tid] = pk;
  }
}

// ---------------- 256x256-tile deep-pipelined batched B^T GEMM ----------------
// C[jg][m][n] = sum_k A[jl][m][k] * B[jl][n][k]
// 512 threads = 8 waves (2 wm x 4 wn); per-wave output 128x64.
// BK=32, 4-deep LDS ring per matrix (4 x 256x32 bf16 = 16 KB each, 128 KB total).
// Staging: 4 x global_load_lds w16 per wave per tile (2 A + 2 B), linear LDS dest,
// inverse-swizzled global source (k-slot ^= (row>>1)&3).
// Reads: ds_read_b128 at slot (lane>>4)^((lane>>1)&3) -> 2-way bank aliasing (free).
// Counted vmcnt(8/4/0); one asm s_barrier per K-tile; setprio around MFMA cluster.
template <int EPI>
__global__ __launch_bounds__(512, 2)
void gemm256(const bf16_t* __restrict__ A, const bf16_t* __restrict__ B,
             float* __restrict__ Cout, const float* __restrict__ bias,
             const float* __restrict__ vin,
             int Mm, int Nn, int Kk, int jBase, int tilesPerJ, int tilesN)
{
  __shared__ char smem[131072];            // [0,64K) = A ring, [64K,128K) = B ring
  int nb = gridDim.x;
  int bid = blockIdx.x;
  if ((nb & 7) == 0) { int cpx = nb >> 3; bid = (bid & 7) * cpx + (bid >> 3); }  // XCD swizzle
  int jl = bid / tilesPerJ;
  int t0 = bid % tilesPerJ;
  int bm = t0 / tilesN, bn = t0 % tilesN;
  int jg = jBase + jl;

  const bf16_t* Aj = A + (size_t)jl * Mm * Kk + (size_t)bm * 256 * Kk;
  const bf16_t* Bj = B + (size_t)jl * Nn * Kk + (size_t)bn * 256 * Kk;

  int tid = threadIdx.x;
  int lane = tid & 63, wid = tid >> 6;
  int wm = wid >> 2, wn = wid & 3;

  // staging: rows wid*16 + (lane>>2) (+128 for second issue); dest slot = lane&3 (linear)
  // source k-slot = (lane&3) ^ ((row>>1)&3) = (lane&3) ^ ((lane>>3)&3)
  int srow = wid * 16 + (lane >> 2);
  int sslot = (lane & 3) ^ ((lane >> 3) & 3);
  const bf16_t* Asrc = Aj + (size_t)srow * Kk + sslot * 8;
  const bf16_t* Bsrc = Bj + (size_t)srow * Kk + sslot * 8;
  int ldsWaveOff = wid * 16 * 64;          // bytes (wave-uniform dest base)

  // compute reads: row = base + (lane&15); want k-slot lane>>4; stored at slot ^ ((row>>1)&3)
  int sp = ((lane >> 4) ^ ((lane >> 1) & 3)) * 16;  // byte offset within 64B row
  int arow = wm * 128 + (lane & 15);
  int brow = wn * 64 + (lane & 15);

  int NT = Kk >> 5;
  f32x4 acc[8][4] = {};

  char* AsBase = smem;
  char* BsBase = smem + 65536;

#define STAGE(tt)                                                              \
  {                                                                            \
    int buf_ = (tt) & 3;                                                       \
    const bf16_t* as_ = Asrc + (size_t)(tt) * 32;                              \
    const bf16_t* bs_ = Bsrc + (size_t)(tt) * 32;                              \
    char* al_ = AsBase + buf_ * 16384 + ldsWaveOff;                            \
    char* bl_ = BsBase + buf_ * 16384 + ldsWaveOff;                            \
    gload16(as_, al_);                                                         \
    gload16(as_ + (size_t)128 * Kk, al_ + 8192);                               \
    gload16(bs_, bl_);                                                         \
    gload16(bs_ + (size_t)128 * Kk, bl_ + 8192);                               \
  }

  STAGE(0);
  if (NT > 1) STAGE(1);
  if (NT > 2) STAGE(2);

  for (int t = 0; t < NT; ++t) {
    // all of this wave's LDS reads of tile t-1 complete before the barrier,
    // so post-barrier STAGE(t+3) may safely overwrite buffer (t-1)&3.
    asm volatile("s_waitcnt lgkmcnt(0)" ::: "memory");
    int rem = NT - 1 - t;
    if (rem >= 2)      asm volatile("s_waitcnt vmcnt(8)" ::: "memory");
    else if (rem == 1) asm volatile("s_waitcnt vmcnt(4)" ::: "memory");
    else               asm volatile("s_waitcnt vmcnt(0)" ::: "memory");
    asm volatile("s_barrier" ::: "memory");
    if (t + 3 < NT) STAGE(t + 3);

    const char* At = AsBase + (t & 3) * 16384;
    const char* Bt = BsBase + (t & 3) * 16384;
    bf16x8 af[8], bfr[4];
#pragma unroll
    for (int i = 0; i < 8; ++i)
      af[i] = *(const bf16x8*)(At + (arow + i * 16) * 64 + sp);
#pragma unroll
    for (int j = 0; j < 4; ++j)
      bfr[j] = *(const bf16x8*)(Bt + (brow + j * 16) * 64 + sp);
    __builtin_amdgcn_s_setprio(1);
#pragma unroll
    for (int i = 0; i < 8; ++i)
#pragma unroll
      for (int j = 0; j < 4; ++j)
        acc[i][j] = __builtin_amdgcn_mfma_f32_16x16x32_bf16(af[i], bfr[j], acc[i][j], 0, 0, 0);
    __builtin_amdgcn_s_setprio(0);
    asm volatile("" ::: "memory");
  }
#undef STAGE

  int rowBase = bm * 256 + wm * 128 + (lane >> 4) * 4;
  int colBase = bn * 256 + wn * 64 + (lane & 15);
  float* Cj = (EPI == 0) ? (Cout + (size_t)jg * Mm * Nn) : Cout;
#pragma unroll
  for (int i = 0; i < 8; ++i) {
#pragma unroll
    for (int j = 0; j < 4; ++j) {
      int gn = colBase + j * 16;
      float bv = 0.f;
      if (EPI == 0) { if (jg == 7) bv = bias[gn]; }
      else bv = bias[gn];
#pragma unroll
      for (int r = 0; r < 4; ++r) {
        int gm = rowBase + i * 16 + r;
        float v = acc[i][j][r] + bv;
        if (EPI == 1) v += vin[(size_t)gm * Nn + gn];
        Cj[(size_t)gm * Nn + gn] = v;
      }
    }
  }
}

// ---------------- attention over 6 kv slabs ----------------
__global__ __launch_bounds__(512)
void attn_fuse(const float* __restrict__ vo, bf16_t* __restrict__ fuse)
{
  int m = blockIdx.x;
  int h = threadIdx.x >> 6;
  int lane = threadIdx.x & 63;
  const size_t slab = (size_t)M_TOK * CDIM;
  const float* base = vo + (size_t)m * CDIM + h * 128;
  float q0 = base[lane], q1 = base[lane + 64];
  float kv0[6], kv1[6], sc[6];
#pragma unroll
  for (int k = 0; k < 6; ++k) {
    const float* kb = base + (size_t)(k + 1) * slab;
    kv0[k] = kb[lane]; kv1[k] = kb[lane + 64];
    sc[k] = q0 * kv0[k] + q1 * kv1[k];
  }
#pragma unroll
  for (int k = 0; k < 6; ++k) {
#pragma unroll
    for (int off = 32; off; off >>= 1) sc[k] += __shfl_xor(sc[k], off);
    sc[k] *= 0.03125f;  // C^-0.5
  }
  float mx = sc[0];
#pragma unroll
  for (int k = 1; k < 6; ++k) mx = fmaxf(mx, sc[k]);
  float e[6], se = 0.f;
#pragma unroll
  for (int k = 0; k < 6; ++k) { e[k] = expf(sc[k] - mx); se += e[k]; }
  float inv = 1.f / se;
  float f0 = 0.f, f1 = 0.f;
#pragma unroll
  for (int k = 0; k < 6; ++k) { float w = e[k] * inv; f0 += w * kv0[k]; f1 += w * kv1[k]; }
  bf16_t* o = fuse + (size_t)m * CDIM + h * 128;
  o[lane] = (bf16_t)f0;
  o[lane + 64] = (bf16_t)f1;
}

// ---------------- cosine per row ----------------
__global__ __launch_bounds__(256)
void cos_row(const float* __restrict__ vf, const float* __restrict__ teacher, float* __restrict__ cosv)
{
  int m = blockIdx.x;
  int tid = threadIdx.x;
  float4 a = ((const float4*)(vf + (size_t)m * CDIM))[tid];
  float4 b = ((const float4*)(teacher + (size_t)m * CDIM))[tid];
  float dot = a.x * b.x + a.y * b.y + a.z * b.z + a.w * b.w;
  float na = a.x * a.x + a.y * a.y + a.z * a.z + a.w * a.w;
  float nb = b.x * b.x + b.y * b.y + b.z * b.z + b.w * b.w;
  int lane = tid & 63, wv = tid >> 6;
#pragma unroll
  for (int off = 32; off; off >>= 1) {
    dot += __shfl_xor(dot, off); na += __shfl_xor(na, off); nb += __shfl_xor(nb, off);
  }
  __shared__ float red[12];
  if (lane == 0) { red[wv] = dot; red[4 + wv] = na; red[8 + wv] = nb; }
  __syncthreads();
  if (tid == 0) {
    float d = red[0] + red[1] + red[2] + red[3];
    float x = red[4] + red[5] + red[6] + red[7];
    float y = red[8] + red[9] + red[10] + red[11];
    float den = fmaxf(sqrtf(x), 1e-8f) * fmaxf(sqrtf(y), 1e-8f);
    cosv[m] = d / den;
  }
}

__global__ __launch_bounds__(256)
void final_reduce(const float* __restrict__ cosv, float* __restrict__ out)
{
  int tid = threadIdx.x;
  float s = 0.f;
  for (int i = tid; i < M_TOK; i += 256) s += cosv[i];
  int lane = tid & 63, wv = tid >> 6;
#pragma unroll
  for (int off = 32; off; off >>= 1) s += __shfl_xor(s, off);
  __shared__ float red[4];
  if (lane == 0) red[wv] = s;
  __syncthreads();
  if (tid == 0) out[0] = 1.f - (red[0] + red[1] + red[2] + red[3]) * (1.f / M_TOK);
}

extern "C" void kernel_launch(void* const* d_in, const int* in_sizes, int n_in,
                              void* d_out, int out_size, void* d_ws, size_t ws_size,
                              hipStream_t stream)
{
  (void)in_sizes; (void)n_in; (void)out_size;
  const float* all_features = (const float*)d_in[0];
  const float* teacher = (const float*)d_in[1];
  const float* ln_gamma = (const float*)d_in[2];
  const float* ln_beta = (const float*)d_in[3];
  const float* norm_w = (const float*)d_in[4];
  const float* input_w = (const float*)d_in[5];
  const float* input_b = (const float*)d_in[6];
  const float* output_w = (const float*)d_in[7];
  const float* output_b = (const float*)d_in[8];
  float* out = (float*)d_out;
  char* ws = (char*)d_ws;

  const size_t M = M_TOK, D = DDIM, C = CDIM;
  const size_t xnB = 8 * M * D * 2;      // 134 MB
  const size_t wbB = 8 * C * D * 2;      // 67 MB
  const size_t owbB = C * C * 2;         // 2 MB
  const size_t voB = 8 * M * C * 4;      // 67 MB (slab7 = vin)
  const size_t fuseB = M * C * 2;
  const size_t vfB = M * C * 4;
  const size_t cosB = M * 4;
  const size_t fastTotal = xnB + wbB + owbB + voB + fuseB + vfB + cosB;

  if (ws_size >= fastTotal) {
    bf16_t* xn = (bf16_t*)ws;
    bf16_t* wb = (bf16_t*)(ws + xnB);
    bf16_t* owb = (bf16_t*)(ws + xnB + wbB);
    float* vo = (float*)(ws + xnB + wbB + owbB);
    bf16_t* fuse = (bf16_t*)(ws + xnB + wbB + owbB + voB);
    float* vf = (float*)(ws + xnB + wbB + owbB + voB + fuseB);
    float* cosv = (float*)(ws + xnB + wbB + owbB + voB + fuseB + vfB);

    cvt_bf16<<<4096, 256, 0, stream>>>(norm_w, wb, (long)7 * C * D);
    cvt_bf16<<<2048, 256, 0, stream>>>(input_w, wb + (size_t)7 * C * D, (long)(C * D));
    cvt_bf16<<<512, 256, 0, stream>>>(output_w, owb, (long)(C * C));
    dim3 g1((unsigned)M, 8);
    ln_convert<<<g1, 256, 0, stream>>>(all_features, ln_gamma, ln_beta, xn, 0);
    gemm256<0><<<256, 512, 0, stream>>>(xn, wb, vo, input_b, nullptr,
                                        (int)M, (int)C, (int)D, 0, 32, 4);
    attn_fuse<<<(unsigned)M, 512, 0, stream>>>(vo, fuse);
    gemm256<1><<<32, 512, 0, stream>>>(fuse, owb, vf, output_b, vo + (size_t)7 * M * C,
                                       (int)M, (int)C, (int)C, 0, 32, 4);
    cos_row<<<(unsigned)M, 256, 0, stream>>>(vf, teacher, cosv);
    final_reduce<<<1, 256, 0, stream>>>(cosv, out);
  } else {
    // SMALL-ws fallback: loop j, reuse one xn/wb slab.
    const size_t xn1B = M * D * 2;
    const size_t wb1B = C * D * 2;
    bf16_t* xn1 = (bf16_t*)ws;
    bf16_t* wb1 = (bf16_t*)(ws + xn1B);
    bf16_t* owb = (bf16_t*)(ws + xn1B + wb1B);
    float* vo = (float*)(ws + xn1B + wb1B + owbB);
    bf16_t* fuse = (bf16_t*)(ws + xn1B + wb1B + owbB + voB);
    float* vf = (float*)(ws + xn1B + wb1B + owbB + voB + fuseB);
    float* cosv = (float*)(ws + xn1B + wb1B + owbB + voB + fuseB + vfB);

    cvt_bf16<<<512, 256, 0, stream>>>(output_w, owb, (long)(C * C));
    for (int j = 0; j < 8; ++j) {
      const float* wsrc = (j < 7) ? (norm_w + (size_t)j * C * D) : input_w;
      cvt_bf16<<<2048, 256, 0, stream>>>(wsrc, wb1, (long)(C * D));
      dim3 g1((unsigned)M, 1);
      ln_convert<<<g1, 256, 0, stream>>>(all_features, ln_gamma, ln_beta, xn1, j);
      gemm256<0><<<32, 512, 0, stream>>>(xn1, wb1, vo, input_b, nullptr,
                                         (int)M, (int)C, (int)D, j, 32, 4);
    }
    attn_fuse<<<(unsigned)M, 512, 0, stream>>>(vo, fuse);
    gemm256<1><<<32, 512, 0, stream>>>(fuse, owb, vf, output_b, vo + (size_t)7 * M * C,
                                       (int)M, (int)C, (int)C, 0, 32, 4);
    cos_row<<<(unsigned)M, 256, 0, stream>>>(vf, teacher, cosv);
    final_reduce<<<1, 256, 0, stream>>>(cosv, out);
  }
}

// Round 4
// 310.577 us; speedup vs baseline: 1.3277x; 1.0204x over previous
//
#include <hip/hip_runtime.h>
#include <cstdint>
#include <cstring>

#define M_TOK 2048   // BT*S
#define DDIM 4096
#define CDIM 1024
#define LTOT 25

typedef __bf16 bf16_t;
typedef __attribute__((ext_vector_type(8))) __bf16 bf16x8;
typedef __attribute__((ext_vector_type(4))) float f32x4;

__device__ __forceinline__ void gload16(const void* g, void* l) {
  __builtin_amdgcn_global_load_lds(
      (const __attribute__((address_space(1))) unsigned int*)g,
      (__attribute__((address_space(3))) unsigned int*)l, 16, 0, 0);
}

// ---------------- fp32 -> bf16 convert ----------------
__global__ void cvt_bf16(const float* __restrict__ src, bf16_t* __restrict__ dst, long n) {
  long stride = (long)gridDim.x * blockDim.x;
  for (long i = (long)blockIdx.x * blockDim.x + threadIdx.x; i * 8 < n; i += stride) {
    const float4* s4 = (const float4*)(src + i * 8);
    float4 a = s4[0], b = s4[1];
    bf16_t o[8] = {(bf16_t)a.x, (bf16_t)a.y, (bf16_t)a.z, (bf16_t)a.w,
                   (bf16_t)b.x, (bf16_t)b.y, (bf16_t)b.z, (bf16_t)b.w};
    uint4 pk;
    __builtin_memcpy(&pk, o, 16);
    *(uint4*)(dst + i * 8) = pk;
  }
}

// ---------------- LayerNorm + gather + bf16 convert ----------------
__global__ __launch_bounds__(256)
void ln_convert(const float* __restrict__ af, const float* __restrict__ gamma,
                const float* __restrict__ beta, bf16_t* __restrict__ xn, int jBase)
{
  int m = blockIdx.x;
  int jl = blockIdx.y;
  int j = jBase + jl;
  int layer = (j < 7) ? (24 - 4 * j) : 24;
  const float4* row4 = (const float4*)(af + ((size_t)m * LTOT + layer) * DDIM);
  int tid = threadIdx.x;
  float4 v[4];
  float s = 0.f, ss = 0.f;
#pragma unroll
  for (int i = 0; i < 4; ++i) {
    v[i] = row4[i * 256 + tid];
    s += v[i].x + v[i].y + v[i].z + v[i].w;
    ss += v[i].x * v[i].x + v[i].y * v[i].y + v[i].z * v[i].z + v[i].w * v[i].w;
  }
  int lane = tid & 63, wv = tid >> 6;
#pragma unroll
  for (int off = 32; off; off >>= 1) { s += __shfl_xor(s, off); ss += __shfl_xor(ss, off); }
  __shared__ float red[8];
  if (lane == 0) { red[wv] = s; red[4 + wv] = ss; }
  __syncthreads();
  s = red[0] + red[1] + red[2] + red[3];
  ss = red[4] + red[5] + red[6] + red[7];
  float mu = 0.f, rs = 1.f;
  if (j < 7) {
    mu = s * (1.f / DDIM);
    float var = ss * (1.f / DDIM) - mu * mu;
    rs = rsqrtf(var + 1e-5f);
  }
  bf16_t* orow = xn + ((size_t)jl * M_TOK + m) * DDIM;
  int jw = (j < 7) ? j : 0;
  const float4* g4 = (const float4*)(gamma + (size_t)jw * DDIM);
  const float4* b4 = (const float4*)(beta + (size_t)jw * DDIM);
#pragma unroll
  for (int i = 0; i < 4; ++i) {
    float4 x = v[i];
    float4 ov;
    if (j < 7) {
      float4 g = g4[i * 256 + tid], bb = b4[i * 256 + tid];
      ov.x = (x.x - mu) * rs * g.x + bb.x;
      ov.y = (x.y - mu) * rs * g.y + bb.y;
      ov.z = (x.z - mu) * rs * g.z + bb.z;
      ov.w = (x.w - mu) * rs * g.w + bb.w;
    } else ov = x;
    bf16_t o[4] = {(bf16_t)ov.x, (bf16_t)ov.y, (bf16_t)ov.z, (bf16_t)ov.w};
    uint2 pk;
    __builtin_memcpy(&pk, o, 8);
    ((uint2*)orow)[i * 256 + tid] = pk;
  }
}

// ---------------- 256x256-tile batched B^T GEMM, reg-double-buffered frags --------
// C[jg][m][n] = sum_k A[jl][m][k] * B[jl][n][k]
// 512 threads = 8 waves (2 wm x 4 wn); per-wave output 128x64.
// BK=32, 4-deep LDS ring (4 x 16 KB per matrix, 128 KB total).
// Fragments for tile t+1 are ds_read in the same barrier window as MFMA(t):
// MFMA cluster starts with operands already resident (no lgkm stall at head).
// vmcnt(4) ladder lands STAGE(u+2) at half-iter u (cross-wave safe 2 barriers ahead).
__global__ __launch_bounds__(512, 2)
void gemm256(const bf16_t* __restrict__ A, const bf16_t* __restrict__ B,
             float* __restrict__ Cout, const float* __restrict__ bias,
             int Mm, int Nn, int Kk, int jBase, int tilesPerJ, int tilesN)
{
  __shared__ char smem[131072];            // [0,64K) = A ring, [64K,128K) = B ring
  int nb = gridDim.x;
  int bid = blockIdx.x;
  if ((nb & 7) == 0) { int cpx = nb >> 3; bid = (bid & 7) * cpx + (bid >> 3); }  // XCD swizzle
  int jl = bid / tilesPerJ;
  int t0 = bid % tilesPerJ;
  int bm = t0 / tilesN, bn = t0 % tilesN;
  int jg = jBase + jl;

  const bf16_t* Aj = A + (size_t)jl * Mm * Kk + (size_t)bm * 256 * Kk;
  const bf16_t* Bj = B + (size_t)jl * Nn * Kk + (size_t)bn * 256 * Kk;

  int tid = threadIdx.x;
  int lane = tid & 63, wid = tid >> 6;
  int wm = wid >> 2, wn = wid & 3;

  // staging: rows wid*16 + (lane>>2) (+128 for second issue); dest slot = lane&3 (linear)
  // source k-slot = (lane&3) ^ ((row>>1)&3) = (lane&3) ^ ((lane>>3)&3)
  int srow = wid * 16 + (lane >> 2);
  int sslot = (lane & 3) ^ ((lane >> 3) & 3);
  const bf16_t* Asrc = Aj + (size_t)srow * Kk + sslot * 8;
  const bf16_t* Bsrc = Bj + (size_t)srow * Kk + sslot * 8;
  int ldsWaveOff = wid * 16 * 64;          // bytes (wave-uniform dest base)

  // compute reads: row = base + (lane&15); want k-slot lane>>4; stored at slot ^ ((row>>1)&3)
  int sp = ((lane >> 4) ^ ((lane >> 1) & 3)) * 16;  // byte offset within 64B row
  int arow = wm * 128 + (lane & 15);
  int brow = wn * 64 + (lane & 15);

  int NT = Kk >> 5;                        // NT even for all our K (128 or 32)
  f32x4 acc[8][4] = {};

  char* AsBase = smem;
  char* BsBase = smem + 65536;

#define STAGE(tt)                                                              \
  {                                                                            \
    int buf_ = (tt) & 3;                                                       \
    const bf16_t* as_ = Asrc + (size_t)(tt) * 32;                              \
    const bf16_t* bs_ = Bsrc + (size_t)(tt) * 32;                              \
    char* al_ = AsBase + buf_ * 16384 + ldsWaveOff;                            \
    char* bl_ = BsBase + buf_ * 16384 + ldsWaveOff;                            \
    gload16(as_, al_);                                                         \
    gload16(as_ + (size_t)128 * Kk, al_ + 8192);                               \
    gload16(bs_, bl_);                                                         \
    gload16(bs_ + (size_t)128 * Kk, bl_ + 8192);                               \
  }

#define LOADFRAG(AF, BF, buf_)                                                 \
  {                                                                            \
    const char* At_ = AsBase + (buf_) * 16384;                                 \
    const char* Bt_ = BsBase + (buf_) * 16384;                                 \
    _Pragma("unroll")                                                          \
    for (int i_ = 0; i_ < 8; ++i_)                                             \
      AF[i_] = *(const bf16x8*)(At_ + (arow + i_ * 16) * 64 + sp);             \
    _Pragma("unroll")                                                          \
    for (int j_ = 0; j_ < 4; ++j_)                                             \
      BF[j_] = *(const bf16x8*)(Bt_ + (brow + j_ * 16) * 64 + sp);             \
  }

#define MFMAS(AF, BF)                                                          \
  {                                                                            \
    __builtin_amdgcn_s_setprio(1);                                             \
    _Pragma("unroll")                                                          \
    for (int i_ = 0; i_ < 8; ++i_)                                             \
      _Pragma("unroll")                                                        \
      for (int j_ = 0; j_ < 4; ++j_)                                           \
        acc[i_][j_] = __builtin_amdgcn_mfma_f32_16x16x32_bf16(                 \
            AF[i_], BF[j_], acc[i_][j_], 0, 0, 0);                             \
    __builtin_amdgcn_s_setprio(0);                                             \
  }

  bf16x8 afA[8], bfrA[4], afB[8], bfrB[4];

  STAGE(0); STAGE(1); STAGE(2); STAGE(3);
  asm volatile("s_waitcnt vmcnt(8)" ::: "memory");   // STAGE(0),(1) landed (own wave)
  asm volatile("s_barrier" ::: "memory");            // publish STAGE(0) across waves
  LOADFRAG(afA, bfrA, 0);
  asm volatile("s_waitcnt lgkmcnt(0)" ::: "memory"); // own frag reads done
  asm volatile("s_barrier" ::: "memory");            // all waves' tile-0 reads done

  for (int t = 0; t < NT; t += 2) {
    // ---- half-iter u = t: compute tile t (set A), read tile t+1 (set B) ----
    if (t + 3 < NT) asm volatile("s_waitcnt vmcnt(4)" ::: "memory");
    else            asm volatile("s_waitcnt vmcnt(0)" ::: "memory");
    if (t + 4 < NT) STAGE(t + 4);
    asm volatile("s_barrier" ::: "memory");
    LOADFRAG(afB, bfrB, (t + 1) & 3);
    MFMAS(afA, bfrA);
    // ---- half-iter u = t+1: compute tile t+1 (set B), read tile t+2 (set A) ----
    if (t + 4 < NT) asm volatile("s_waitcnt vmcnt(4)" ::: "memory");
    else            asm volatile("s_waitcnt vmcnt(0)" ::: "memory");
    if (t + 5 < NT) STAGE(t + 5);
    asm volatile("s_barrier" ::: "memory");
    if (t + 2 < NT) LOADFRAG(afA, bfrA, (t + 2) & 3);
    MFMAS(afB, bfrB);
  }
#undef STAGE
#undef LOADFRAG
#undef MFMAS

  int rowBase = bm * 256 + wm * 128 + (lane >> 4) * 4;
  int colBase = bn * 256 + wn * 64 + (lane & 15);
  float* Cj = Cout + (size_t)jg * Mm * Nn;
#pragma unroll
  for (int i = 0; i < 8; ++i) {
#pragma unroll
    for (int j = 0; j < 4; ++j) {
      int gn = colBase + j * 16;
      float bv = (jg == 7) ? bias[gn] : 0.f;
#pragma unroll
      for (int r = 0; r < 4; ++r) {
        int gm = rowBase + i * 16 + r;
        Cj[(size_t)gm * Nn + gn] = acc[i][j][r] + bv;
      }
    }
  }
}

// ---------------- 128x128-tile GEMM (proven) for the output projection ----------------
// C[m][n] = sum_k A[m][k]*B[n][k] + bias[n] + vin[m][n]
__global__ __launch_bounds__(256)
void gemm_bt_epi(const bf16_t* __restrict__ A, const bf16_t* __restrict__ B,
                 float* __restrict__ Cout, const float* __restrict__ bias,
                 const float* __restrict__ vin, int Mm, int Nn, int Kk, int tilesN)
{
  __shared__ bf16_t As[128 * 64];
  __shared__ bf16_t Bs[128 * 64];
  int bid = blockIdx.x;
  int bm = bid / tilesN, bn = bid % tilesN;
  const bf16_t* Aj = A + (size_t)bm * 128 * Kk;
  const bf16_t* Bj = B + (size_t)bn * 128 * Kk;

  int tid = threadIdx.x;
  int lane = tid & 63, wv = tid >> 6;
  int wm = wv >> 1, wn = wv & 1;

  f32x4 acc[4][4] = {};

  int srow = wv * 32 + (lane >> 3);
  int scol = (lane & 7) * 8;
  const bf16_t* Ag = Aj + (size_t)srow * Kk + scol;
  const bf16_t* Bg = Bj + (size_t)srow * Kk + scol;

  for (int kt = 0; kt < Kk; kt += 64) {
#pragma unroll
    for (int c = 0; c < 4; ++c) {
      gload16(Ag + kt + (size_t)(c * 8) * Kk, &As[(wv * 32 + c * 8) * 64]);
      gload16(Bg + kt + (size_t)(c * 8) * Kk, &Bs[(wv * 32 + c * 8) * 64]);
    }
    __syncthreads();
#pragma unroll
    for (int ks = 0; ks < 2; ++ks) {
      int ko = ks * 32 + (lane >> 4) * 8;
      bf16x8 af[4], bfr[4];
#pragma unroll
      for (int i = 0; i < 4; ++i) {
        af[i] = *(const bf16x8*)&As[(wm * 64 + i * 16 + (lane & 15)) * 64 + ko];
        bfr[i] = *(const bf16x8*)&Bs[(wn * 64 + i * 16 + (lane & 15)) * 64 + ko];
      }
#pragma unroll
      for (int i = 0; i < 4; ++i)
#pragma unroll
        for (int j2 = 0; j2 < 4; ++j2)
          acc[i][j2] = __builtin_amdgcn_mfma_f32_16x16x32_bf16(af[i], bfr[j2], acc[i][j2], 0, 0, 0);
    }
    __syncthreads();
  }

  int rowBase = bm * 128 + wm * 64 + (lane >> 4) * 4;
  int colBase = bn * 128 + wn * 64 + (lane & 15);
#pragma unroll
  for (int i = 0; i < 4; ++i) {
#pragma unroll
    for (int j2 = 0; j2 < 4; ++j2) {
      int gn = colBase + j2 * 16;
      float bv = bias[gn];
#pragma unroll
      for (int r = 0; r < 4; ++r) {
        int gm = rowBase + i * 16 + r;
        Cout[(size_t)gm * Nn + gn] = acc[i][j2][r] + bv + vin[(size_t)gm * Nn + gn];
      }
    }
  }
}

// ---------------- attention over 6 kv slabs ----------------
__global__ __launch_bounds__(512)
void attn_fuse(const float* __restrict__ vo, bf16_t* __restrict__ fuse)
{
  int m = blockIdx.x;
  int h = threadIdx.x >> 6;
  int lane = threadIdx.x & 63;
  const size_t slab = (size_t)M_TOK * CDIM;
  const float* base = vo + (size_t)m * CDIM + h * 128;
  float q0 = base[lane], q1 = base[lane + 64];
  float kv0[6], kv1[6], sc[6];
#pragma unroll
  for (int k = 0; k < 6; ++k) {
    const float* kb = base + (size_t)(k + 1) * slab;
    kv0[k] = kb[lane]; kv1[k] = kb[lane + 64];
    sc[k] = q0 * kv0[k] + q1 * kv1[k];
  }
#pragma unroll
  for (int k = 0; k < 6; ++k) {
#pragma unroll
    for (int off = 32; off; off >>= 1) sc[k] += __shfl_xor(sc[k], off);
    sc[k] *= 0.03125f;  // C^-0.5
  }
  float mx = sc[0];
#pragma unroll
  for (int k = 1; k < 6; ++k) mx = fmaxf(mx, sc[k]);
  float e[6], se = 0.f;
#pragma unroll
  for (int k = 0; k < 6; ++k) { e[k] = expf(sc[k] - mx); se += e[k]; }
  float inv = 1.f / se;
  float f0 = 0.f, f1 = 0.f;
#pragma unroll
  for (int k = 0; k < 6; ++k) { float w = e[k] * inv; f0 += w * kv0[k]; f1 += w * kv1[k]; }
  bf16_t* o = fuse + (size_t)m * CDIM + h * 128;
  o[lane] = (bf16_t)f0;
  o[lane + 64] = (bf16_t)f1;
}

// ---------------- cosine per row ----------------
__global__ __launch_bounds__(256)
void cos_row(const float* __restrict__ vf, const float* __restrict__ teacher, float* __restrict__ cosv)
{
  int m = blockIdx.x;
  int tid = threadIdx.x;
  float4 a = ((const float4*)(vf + (size_t)m * CDIM))[tid];
  float4 b = ((const float4*)(teacher + (size_t)m * CDIM))[tid];
  float dot = a.x * b.x + a.y * b.y + a.z * b.z + a.w * b.w;
  float na = a.x * a.x + a.y * a.y + a.z * a.z + a.w * a.w;
  float nb = b.x * b.x + b.y * b.y + b.z * b.z + b.w * b.w;
  int lane = tid & 63, wv = tid >> 6;
#pragma unroll
  for (int off = 32; off; off >>= 1) {
    dot += __shfl_xor(dot, off); na += __shfl_xor(na, off); nb += __shfl_xor(nb, off);
  }
  __shared__ float red[12];
  if (lane == 0) { red[wv] = dot; red[4 + wv] = na; red[8 + wv] = nb; }
  __syncthreads();
  if (tid == 0) {
    float d = red[0] + red[1] + red[2] + red[3];
    float x = red[4] + red[5] + red[6] + red[7];
    float y = red[8] + red[9] + red[10] + red[11];
    float den = fmaxf(sqrtf(x), 1e-8f) * fmaxf(sqrtf(y), 1e-8f);
    cosv[m] = d / den;
  }
}

__global__ __launch_bounds__(256)
void final_reduce(const float* __restrict__ cosv, float* __restrict__ out)
{
  int tid = threadIdx.x;
  float s = 0.f;
  for (int i = tid; i < M_TOK; i += 256) s += cosv[i];
  int lane = tid & 63, wv = tid >> 6;
#pragma unroll
  for (int off = 32; off; off >>= 1) s += __shfl_xor(s, off);
  __shared__ float red[4];
  if (lane == 0) red[wv] = s;
  __syncthreads();
  if (tid == 0) out[0] = 1.f - (red[0] + red[1] + red[2] + red[3]) * (1.f / M_TOK);
}

extern "C" void kernel_launch(void* const* d_in, const int* in_sizes, int n_in,
                              void* d_out, int out_size, void* d_ws, size_t ws_size,
                              hipStream_t stream)
{
  (void)in_sizes; (void)n_in; (void)out_size;
  const float* all_features = (const float*)d_in[0];
  const float* teacher = (const float*)d_in[1];
  const float* ln_gamma = (const float*)d_in[2];
  const float* ln_beta = (const float*)d_in[3];
  const float* norm_w = (const float*)d_in[4];
  const float* input_w = (const float*)d_in[5];
  const float* input_b = (const float*)d_in[6];
  const float* output_w = (const float*)d_in[7];
  const float* output_b = (const float*)d_in[8];
  float* out = (float*)d_out;
  char* ws = (char*)d_ws;

  const size_t M = M_TOK, D = DDIM, C = CDIM;
  const size_t xnB = 8 * M * D * 2;      // 134 MB
  const size_t wbB = 8 * C * D * 2;      // 67 MB
  const size_t owbB = C * C * 2;         // 2 MB
  const size_t voB = 8 * M * C * 4;      // 67 MB (slab7 = vin)
  const size_t fuseB = M * C * 2;
  const size_t vfB = M * C * 4;
  const size_t cosB = M * 4;
  const size_t fastTotal = xnB + wbB + owbB + voB + fuseB + vfB + cosB;

  if (ws_size >= fastTotal) {
    bf16_t* xn = (bf16_t*)ws;
    bf16_t* wb = (bf16_t*)(ws + xnB);
    bf16_t* owb = (bf16_t*)(ws + xnB + wbB);
    float* vo = (float*)(ws + xnB + wbB + owbB);
    bf16_t* fuse = (bf16_t*)(ws + xnB + wbB + owbB + voB);
    float* vf = (float*)(ws + xnB + wbB + owbB + voB + fuseB);
    float* cosv = (float*)(ws + xnB + wbB + owbB + voB + fuseB + vfB);

    cvt_bf16<<<4096, 256, 0, stream>>>(norm_w, wb, (long)7 * C * D);
    cvt_bf16<<<2048, 256, 0, stream>>>(input_w, wb + (size_t)7 * C * D, (long)(C * D));
    cvt_bf16<<<512, 256, 0, stream>>>(output_w, owb, (long)(C * C));
    dim3 g1((unsigned)M, 8);
    ln_convert<<<g1, 256, 0, stream>>>(all_features, ln_gamma, ln_beta, xn, 0);
    gemm256<<<256, 512, 0, stream>>>(xn, wb, vo, input_b,
                                     (int)M, (int)C, (int)D, 0, 32, 4);
    attn_fuse<<<(unsigned)M, 512, 0, stream>>>(vo, fuse);
    gemm_bt_epi<<<128, 256, 0, stream>>>(fuse, owb, vf, output_b, vo + (size_t)7 * M * C,
                                         (int)M, (int)C, (int)C, 8);
    cos_row<<<(unsigned)M, 256, 0, stream>>>(vf, teacher, cosv);
    final_reduce<<<1, 256, 0, stream>>>(cosv, out);
  } else {
    // SMALL-ws fallback: loop j, reuse one xn/wb slab.
    const size_t xn1B = M * D * 2;
    const size_t wb1B = C * D * 2;
    bf16_t* xn1 = (bf16_t*)ws;
    bf16_t* wb1 = (bf16_t*)(ws + xn1B);
    bf16_t* owb = (bf16_t*)(ws + xn1B + wb1B);
    float* vo = (float*)(ws + xn1B + wb1B + owbB);
    bf16_t* fuse = (bf16_t*)(ws + xn1B + wb1B + owbB + voB);
    float* vf = (float*)(ws + xn1B + wb1B + owbB + voB + fuseB);
    float* cosv = (float*)(ws + xn1B + wb1B + owbB + voB + fuseB + vfB);

    cvt_bf16<<<512, 256, 0, stream>>>(output_w, owb, (long)(C * C));
    for (int j = 0; j < 8; ++j) {
      const float* wsrc = (j < 7) ? (norm_w + (size_t)j * C * D) : input_w;
      cvt_bf16<<<2048, 256, 0, stream>>>(wsrc, wb1, (long)(C * D));
      dim3 g1((unsigned)M, 1);
      ln_convert<<<g1, 256, 0, stream>>>(all_features, ln_gamma, ln_beta, xn1, j);
      gemm256<<<32, 512, 0, stream>>>(xn1, wb1, vo, input_b,
                                      (int)M, (int)C, (int)D, j, 32, 4);
    }
    attn_fuse<<<(unsigned)M, 512, 0, stream>>>(vo, fuse);
    gemm_bt_epi<<<128, 256, 0, stream>>>(fuse, owb, vf, output_b, vo + (size_t)7 * M * C,
                                         (int)M, (int)C, (int)C, 8);
    cos_row<<<(unsigned)M, 256, 0, stream>>>(vf, teacher, cosv);
    final_reduce<<<1, 256, 0, stream>>>(cosv, out);
  }
}

// Round 5
// 301.181 us; speedup vs baseline: 1.3691x; 1.0312x over previous
//
#include <hip/hip_runtime.h>
#include <cstdint>
#include <cstring>

#define M_TOK 2048   // BT*S
#define DDIM 4096
#define CDIM 1024
#define LTOT 25

typedef __bf16 bf16_t;
typedef __attribute__((ext_vector_type(8))) __bf16 bf16x8;
typedef __attribute__((ext_vector_type(4))) float f32x4;

__device__ __forceinline__ void gload16(const void* g, void* l) {
  __builtin_amdgcn_global_load_lds(
      (const __attribute__((address_space(1))) unsigned int*)g,
      (__attribute__((address_space(3))) unsigned int*)l, 16, 0, 0);
}

// ---------------- fp32 -> bf16 convert ----------------
__global__ void cvt_bf16(const float* __restrict__ src, bf16_t* __restrict__ dst, long n) {
  long stride = (long)gridDim.x * blockDim.x;
  for (long i = (long)blockIdx.x * blockDim.x + threadIdx.x; i * 8 < n; i += stride) {
    const float4* s4 = (const float4*)(src + i * 8);
    float4 a = s4[0], b = s4[1];
    bf16_t o[8] = {(bf16_t)a.x, (bf16_t)a.y, (bf16_t)a.z, (bf16_t)a.w,
                   (bf16_t)b.x, (bf16_t)b.y, (bf16_t)b.z, (bf16_t)b.w};
    uint4 pk;
    __builtin_memcpy(&pk, o, 16);
    *(uint4*)(dst + i * 8) = pk;
  }
}

// ---------------- LayerNorm + gather + bf16 convert ----------------
__global__ __launch_bounds__(256)
void ln_convert(const float* __restrict__ af, const float* __restrict__ gamma,
                const float* __restrict__ beta, bf16_t* __restrict__ xn, int jBase)
{
  int m = blockIdx.x;
  int jl = blockIdx.y;
  int j = jBase + jl;
  int layer = (j < 7) ? (24 - 4 * j) : 24;
  const float4* row4 = (const float4*)(af + ((size_t)m * LTOT + layer) * DDIM);
  int tid = threadIdx.x;
  float4 v[4];
  float s = 0.f, ss = 0.f;
#pragma unroll
  for (int i = 0; i < 4; ++i) {
    v[i] = row4[i * 256 + tid];
    s += v[i].x + v[i].y + v[i].z + v[i].w;
    ss += v[i].x * v[i].x + v[i].y * v[i].y + v[i].z * v[i].z + v[i].w * v[i].w;
  }
  int lane = tid & 63, wv = tid >> 6;
#pragma unroll
  for (int off = 32; off; off >>= 1) { s += __shfl_xor(s, off); ss += __shfl_xor(ss, off); }
  __shared__ float red[8];
  if (lane == 0) { red[wv] = s; red[4 + wv] = ss; }
  __syncthreads();
  s = red[0] + red[1] + red[2] + red[3];
  ss = red[4] + red[5] + red[6] + red[7];
  float mu = 0.f, rs = 1.f;
  if (j < 7) {
    mu = s * (1.f / DDIM);
    float var = ss * (1.f / DDIM) - mu * mu;
    rs = rsqrtf(var + 1e-5f);
  }
  bf16_t* orow = xn + ((size_t)jl * M_TOK + m) * DDIM;
  int jw = (j < 7) ? j : 0;
  const float4* g4 = (const float4*)(gamma + (size_t)jw * DDIM);
  const float4* b4 = (const float4*)(beta + (size_t)jw * DDIM);
#pragma unroll
  for (int i = 0; i < 4; ++i) {
    float4 x = v[i];
    float4 ov;
    if (j < 7) {
      float4 g = g4[i * 256 + tid], bb = b4[i * 256 + tid];
      ov.x = (x.x - mu) * rs * g.x + bb.x;
      ov.y = (x.y - mu) * rs * g.y + bb.y;
      ov.z = (x.z - mu) * rs * g.z + bb.z;
      ov.w = (x.w - mu) * rs * g.w + bb.w;
    } else ov = x;
    bf16_t o[4] = {(bf16_t)ov.x, (bf16_t)ov.y, (bf16_t)ov.z, (bf16_t)ov.w};
    uint2 pk;
    __builtin_memcpy(&pk, o, 8);
    ((uint2*)orow)[i * 256 + tid] = pk;
  }
}

// ---------------- 256x256-tile 8-phase batched B^T GEMM (m201 schedule) ----------
// C[jg][m][n] = sum_k A[jl][m][k] * B[jl][n][k]
// 512 threads = 8 waves (2 wm x 4 wn); per-wave output 128x64. BK=64.
// LDS: 2 bufs x (A 256x64 + B 256x64) bf16 = 128 KB. Chunk = 64 rows (8 KB,
// one gload16/thread). Per K-tile, 4 phases (quadrant ih x jh), each:
//   {ds_read new frags || stage 2 chunks of t+1} -> barrier -> lgkmcnt(0)
//   -> setprio(1) 16 MFMA setprio(0) -> [vmcnt(4)@ph1 / vmcnt(2)@ph3] -> barrier
// Swizzle (both-sides involution, rule 21): linear gload dest; source k-slot
// pre-swizzled by (l&7)^((l>>3)&7); read slot ((k<<2)|(lane>>4))^(lane&7).
__global__ __launch_bounds__(512, 2)
void gemm256(const bf16_t* __restrict__ A, const bf16_t* __restrict__ B,
             float* __restrict__ Cout, const float* __restrict__ bias,
             int Mm, int Nn, int Kk, int jBase, int tilesPerJ, int tilesN)
{
  __shared__ __align__(16) char smem[131072];  // [0,64K) A bufs, [64K,128K) B bufs
  int nb = gridDim.x;
  int bid = blockIdx.x;
  if ((nb & 7) == 0) { int cpx = nb >> 3; bid = (bid & 7) * cpx + (bid >> 3); }  // XCD swizzle
  int jl = bid / tilesPerJ;
  int t0 = bid % tilesPerJ;
  int bm = t0 / tilesN, bn = t0 % tilesN;
  int jg = jBase + jl;

  const bf16_t* Aj = A + (size_t)jl * Mm * Kk + (size_t)bm * 256 * Kk;
  const bf16_t* Bj = B + (size_t)jl * Nn * Kk + (size_t)bn * 256 * Kk;

  int tid = threadIdx.x;
  int lane = tid & 63, wid = tid >> 6;
  int wm = wid >> 2, wn = wid & 3;
  int wm2 = wm * 2;

  // staging source (per chunk c, tile tt): row = c*64 + wid*8 + (lane>>3),
  // k-slot pre-swizzle gslot = (lane&7)^((lane>>3)&7)
  const bf16_t* Ast = Aj + (size_t)(wid * 8 + (lane >> 3)) * Kk + ((lane & 7) ^ ((lane >> 3) & 7)) * 8;
  const bf16_t* Bst = Bj + (size_t)(wid * 8 + (lane >> 3)) * Kk + ((lane & 7) ^ ((lane >> 3) & 7)) * 8;

  // read addressing
  int rb = lane & 15;
  int s0 = (((lane >> 4)) ^ (lane & 7)) * 16;      // k-slice 0 byte offset in 128B row
  int s1 = ((4 | (lane >> 4)) ^ (lane & 7)) * 16;  // k-slice 1

  int NT = Kk >> 6;
  f32x4 acc[8][4] = {};
  bf16x8 Af[4][2], Bf[4][2];

#define STAGEA(c_, tt_)                                                          \
  gload16(Ast + (size_t)(c_) * 64 * Kk + (size_t)(tt_) * 64,                     \
          &smem[(((tt_) & 1) * 32768) + (c_) * 8192 + wid * 1024])
#define STAGEB(c_, tt_)                                                          \
  gload16(Bst + (size_t)(c_) * 64 * Kk + (size_t)(tt_) * 64,                     \
          &smem[65536 + (((tt_) & 1) * 32768) + (c_) * 8192 + wid * 1024])

#define LOADA(buf_, ih_)                                                         \
  { const char* Ac_ = &smem[(buf_) * 32768 + (wm2 + (ih_)) * 8192];              \
    _Pragma("unroll")                                                            \
    for (int ip_ = 0; ip_ < 4; ++ip_) {                                          \
      Af[ip_][0] = *(const bf16x8*)(Ac_ + (ip_ * 16 + rb) * 128 + s0);           \
      Af[ip_][1] = *(const bf16x8*)(Ac_ + (ip_ * 16 + rb) * 128 + s1);           \
    } }

#define LOADB(buf_, jh_)                                                         \
  { const char* Bc_ = &smem[65536 + (buf_) * 32768 + wn * 8192];                 \
    _Pragma("unroll")                                                            \
    for (int jp_ = 0; jp_ < 2; ++jp_) {                                          \
      Bf[(jh_) * 2 + jp_][0] = *(const bf16x8*)(Bc_ + (((jh_) * 2 + jp_) * 16 + rb) * 128 + s0); \
      Bf[(jh_) * 2 + jp_][1] = *(const bf16x8*)(Bc_ + (((jh_) * 2 + jp_) * 16 + rb) * 128 + s1); \
    } }

#define MFMAQ(ih_, jh_)                                                          \
  { __builtin_amdgcn_s_setprio(1);                                               \
    _Pragma("unroll")                                                            \
    for (int ip_ = 0; ip_ < 4; ++ip_)                                            \
      _Pragma("unroll")                                                          \
      for (int jp_ = 0; jp_ < 2; ++jp_)                                          \
        _Pragma("unroll")                                                        \
        for (int k_ = 0; k_ < 2; ++k_)                                           \
          acc[(ih_) * 4 + ip_][(jh_) * 2 + jp_] =                                \
              __builtin_amdgcn_mfma_f32_16x16x32_bf16(                           \
                  Af[ip_][k_], Bf[(jh_) * 2 + jp_][k_],                          \
                  acc[(ih_) * 4 + ip_][(jh_) * 2 + jp_], 0, 0, 0);               \
    __builtin_amdgcn_s_setprio(0); }

#define BAR() asm volatile("s_barrier" ::: "memory")
#define LGKM0() asm volatile("s_waitcnt lgkmcnt(0)" ::: "memory")

  // prologue: stage tile 0 in consumption order; allow A1,A3 in flight
  STAGEB(0, 0); STAGEB(1, 0); STAGEB(2, 0); STAGEB(3, 0);
  STAGEA(0, 0); STAGEA(2, 0); STAGEA(1, 0); STAGEA(3, 0);
  asm volatile("s_waitcnt vmcnt(2)" ::: "memory");
  BAR();

#pragma unroll 1
  for (int t = 0; t < NT; ++t) {
    int buf = t & 1;
    int tn = t + 1;
    bool more = tn < NT;
    // ---- phase 0: quadrant (ih0,jh0); stage B0,B1 of t+1 ----
    LOADA(buf, 0);
    LOADB(buf, 0);
    if (more) { STAGEB(0, tn); STAGEB(1, tn); }
    BAR(); LGKM0();
    MFMAQ(0, 0);
    BAR();
    // ---- phase 1: quadrant (ih0,jh1); stage B2,B3 ----
    LOADB(buf, 1);
    if (more) { STAGEB(2, tn); STAGEB(3, tn); }
    BAR(); LGKM0();
    MFMAQ(0, 1);
    if (more) asm volatile("s_waitcnt vmcnt(4)" ::: "memory");
    else      asm volatile("s_waitcnt vmcnt(0)" ::: "memory");
    BAR();
    // ---- phase 2: quadrant (ih1,jh0); stage A0,A2 ----
    LOADA(buf, 1);
    if (more) { STAGEA(0, tn); STAGEA(2, tn); }
    BAR(); LGKM0();
    MFMAQ(1, 0);
    BAR();
    // ---- phase 3: quadrant (ih1,jh1); stage A1,A3 ----
    if (more) { STAGEA(1, tn); STAGEA(3, tn); }
    BAR(); LGKM0();
    MFMAQ(1, 1);
    if (more) asm volatile("s_waitcnt vmcnt(2)" ::: "memory");
    BAR();
  }
#undef STAGEA
#undef STAGEB
#undef LOADA
#undef LOADB
#undef MFMAQ
#undef BAR
#undef LGKM0

  int rowBase = bm * 256 + wm * 128 + (lane >> 4) * 4;
  int colBase = bn * 256 + wn * 64 + (lane & 15);
  float* Cj = Cout + (size_t)jg * Mm * Nn;
#pragma unroll
  for (int i = 0; i < 8; ++i) {
#pragma unroll
    for (int j = 0; j < 4; ++j) {
      int gn = colBase + j * 16;
      float bv = (jg == 7) ? bias[gn] : 0.f;
#pragma unroll
      for (int r = 0; r < 4; ++r) {
        int gm = rowBase + i * 16 + r;
        Cj[(size_t)gm * Nn + gn] = acc[i][j][r] + bv;
      }
    }
  }
}

// ---------------- 128x128-tile GEMM (proven) for the output projection ----------------
// C[m][n] = sum_k A[m][k]*B[n][k] + bias[n] + vin[m][n]
__global__ __launch_bounds__(256)
void gemm_bt_epi(const bf16_t* __restrict__ A, const bf16_t* __restrict__ B,
                 float* __restrict__ Cout, const float* __restrict__ bias,
                 const float* __restrict__ vin, int Mm, int Nn, int Kk, int tilesN)
{
  __shared__ bf16_t As[128 * 64];
  __shared__ bf16_t Bs[128 * 64];
  int bid = blockIdx.x;
  int bm = bid / tilesN, bn = bid % tilesN;
  const bf16_t* Aj = A + (size_t)bm * 128 * Kk;
  const bf16_t* Bj = B + (size_t)bn * 128 * Kk;

  int tid = threadIdx.x;
  int lane = tid & 63, wv = tid >> 6;
  int wm = wv >> 1, wn = wv & 1;

  f32x4 acc[4][4] = {};

  int srow = wv * 32 + (lane >> 3);
  int scol = (lane & 7) * 8;
  const bf16_t* Ag = Aj + (size_t)srow * Kk + scol;
  const bf16_t* Bg = Bj + (size_t)srow * Kk + scol;

  for (int kt = 0; kt < Kk; kt += 64) {
#pragma unroll
    for (int c = 0; c < 4; ++c) {
      gload16(Ag + kt + (size_t)(c * 8) * Kk, &As[(wv * 32 + c * 8) * 64]);
      gload16(Bg + kt + (size_t)(c * 8) * Kk, &Bs[(wv * 32 + c * 8) * 64]);
    }
    __syncthreads();
#pragma unroll
    for (int ks = 0; ks < 2; ++ks) {
      int ko = ks * 32 + (lane >> 4) * 8;
      bf16x8 af[4], bfr[4];
#pragma unroll
      for (int i = 0; i < 4; ++i) {
        af[i] = *(const bf16x8*)&As[(wm * 64 + i * 16 + (lane & 15)) * 64 + ko];
        bfr[i] = *(const bf16x8*)&Bs[(wn * 64 + i * 16 + (lane & 15)) * 64 + ko];
      }
#pragma unroll
      for (int i = 0; i < 4; ++i)
#pragma unroll
        for (int j2 = 0; j2 < 4; ++j2)
          acc[i][j2] = __builtin_amdgcn_mfma_f32_16x16x32_bf16(af[i], bfr[j2], acc[i][j2], 0, 0, 0);
    }
    __syncthreads();
  }

  int rowBase = bm * 128 + wm * 64 + (lane >> 4) * 4;
  int colBase = bn * 128 + wn * 64 + (lane & 15);
#pragma unroll
  for (int i = 0; i < 4; ++i) {
#pragma unroll
    for (int j2 = 0; j2 < 4; ++j2) {
      int gn = colBase + j2 * 16;
      float bv = bias[gn];
#pragma unroll
      for (int r = 0; r < 4; ++r) {
        int gm = rowBase + i * 16 + r;
        Cout[(size_t)gm * Nn + gn] = acc[i][j2][r] + bv + vin[(size_t)gm * Nn + gn];
      }
    }
  }
}

// ---------------- attention over 6 kv slabs ----------------
__global__ __launch_bounds__(512)
void attn_fuse(const float* __restrict__ vo, bf16_t* __restrict__ fuse)
{
  int m = blockIdx.x;
  int h = threadIdx.x >> 6;
  int lane = threadIdx.x & 63;
  const size_t slab = (size_t)M_TOK * CDIM;
  const float* base = vo + (size_t)m * CDIM + h * 128;
  float q0 = base[lane], q1 = base[lane + 64];
  float kv0[6], kv1[6], sc[6];
#pragma unroll
  for (int k = 0; k < 6; ++k) {
    const float* kb = base + (size_t)(k + 1) * slab;
    kv0[k] = kb[lane]; kv1[k] = kb[lane + 64];
    sc[k] = q0 * kv0[k] + q1 * kv1[k];
  }
#pragma unroll
  for (int k = 0; k < 6; ++k) {
#pragma unroll
    for (int off = 32; off; off >>= 1) sc[k] += __shfl_xor(sc[k], off);
    sc[k] *= 0.03125f;  // C^-0.5
  }
  float mx = sc[0];
#pragma unroll
  for (int k = 1; k < 6; ++k) mx = fmaxf(mx, sc[k]);
  float e[6], se = 0.f;
#pragma unroll
  for (int k = 0; k < 6; ++k) { e[k] = expf(sc[k] - mx); se += e[k]; }
  float inv = 1.f / se;
  float f0 = 0.f, f1 = 0.f;
#pragma unroll
  for (int k = 0; k < 6; ++k) { float w = e[k] * inv; f0 += w * kv0[k]; f1 += w * kv1[k]; }
  bf16_t* o = fuse + (size_t)m * CDIM + h * 128;
  o[lane] = (bf16_t)f0;
  o[lane + 64] = (bf16_t)f1;
}

// ---------------- cosine per row ----------------
__global__ __launch_bounds__(256)
void cos_row(const float* __restrict__ vf, const float* __restrict__ teacher, float* __restrict__ cosv)
{
  int m = blockIdx.x;
  int tid = threadIdx.x;
  float4 a = ((const float4*)(vf + (size_t)m * CDIM))[tid];
  float4 b = ((const float4*)(teacher + (size_t)m * CDIM))[tid];
  float dot = a.x * b.x + a.y * b.y + a.z * b.z + a.w * b.w;
  float na = a.x * a.x + a.y * a.y + a.z * a.z + a.w * a.w;
  float nb = b.x * b.x + b.y * b.y + b.z * b.z + b.w * b.w;
  int lane = tid & 63, wv = tid >> 6;
#pragma unroll
  for (int off = 32; off; off >>= 1) {
    dot += __shfl_xor(dot, off); na += __shfl_xor(na, off); nb += __shfl_xor(nb, off);
  }
  __shared__ float red[12];
  if (lane == 0) { red[wv] = dot; red[4 + wv] = na; red[8 + wv] = nb; }
  __syncthreads();
  if (tid == 0) {
    float d = red[0] + red[1] + red[2] + red[3];
    float x = red[4] + red[5] + red[6] + red[7];
    float y = red[8] + red[9] + red[10] + red[11];
    float den = fmaxf(sqrtf(x), 1e-8f) * fmaxf(sqrtf(y), 1e-8f);
    cosv[m] = d / den;
  }
}

__global__ __launch_bounds__(256)
void final_reduce(const float* __restrict__ cosv, float* __restrict__ out)
{
  int tid = threadIdx.x;
  float s = 0.f;
  for (int i = tid; i < M_TOK; i += 256) s += cosv[i];
  int lane = tid & 63, wv = tid >> 6;
#pragma unroll
  for (int off = 32; off; off >>= 1) s += __shfl_xor(s, off);
  __shared__ float red[4];
  if (lane == 0) red[wv] = s;
  __syncthreads();
  if (tid == 0) out[0] = 1.f - (red[0] + red[1] + red[2] + red[3]) * (1.f / M_TOK);
}

extern "C" void kernel_launch(void* const* d_in, const int* in_sizes, int n_in,
                              void* d_out, int out_size, void* d_ws, size_t ws_size,
                              hipStream_t stream)
{
  (void)in_sizes; (void)n_in; (void)out_size;
  const float* all_features = (const float*)d_in[0];
  const float* teacher = (const float*)d_in[1];
  const float* ln_gamma = (const float*)d_in[2];
  const float* ln_beta = (const float*)d_in[3];
  const float* norm_w = (const float*)d_in[4];
  const float* input_w = (const float*)d_in[5];
  const float* input_b = (const float*)d_in[6];
  const float* output_w = (const float*)d_in[7];
  const float* output_b = (const float*)d_in[8];
  float* out = (float*)d_out;
  char* ws = (char*)d_ws;

  const size_t M = M_TOK, D = DDIM, C = CDIM;
  const size_t xnB = 8 * M * D * 2;      // 134 MB
  const size_t wbB = 8 * C * D * 2;      // 67 MB
  const size_t owbB = C * C * 2;         // 2 MB
  const size_t voB = 8 * M * C * 4;      // 67 MB (slab7 = vin)
  const size_t fuseB = M * C * 2;
  const size_t vfB = M * C * 4;
  const size_t cosB = M * 4;
  const size_t fastTotal = xnB + wbB + owbB + voB + fuseB + vfB + cosB;

  if (ws_size >= fastTotal) {
    bf16_t* xn = (bf16_t*)ws;
    bf16_t* wb = (bf16_t*)(ws + xnB);
    bf16_t* owb = (bf16_t*)(ws + xnB + wbB);
    float* vo = (float*)(ws + xnB + wbB + owbB);
    bf16_t* fuse = (bf16_t*)(ws + xnB + wbB + owbB + voB);
    float* vf = (float*)(ws + xnB + wbB + owbB + voB + fuseB);
    float* cosv = (float*)(ws + xnB + wbB + owbB + voB + fuseB + vfB);

    cvt_bf16<<<4096, 256, 0, stream>>>(norm_w, wb, (long)7 * C * D);
    cvt_bf16<<<2048, 256, 0, stream>>>(input_w, wb + (size_t)7 * C * D, (long)(C * D));
    cvt_bf16<<<512, 256, 0, stream>>>(output_w, owb, (long)(C * C));
    dim3 g1((unsigned)M, 8);
    ln_convert<<<g1, 256, 0, stream>>>(all_features, ln_gamma, ln_beta, xn, 0);
    gemm256<<<256, 512, 0, stream>>>(xn, wb, vo, input_b,
                                     (int)M, (int)C, (int)D, 0, 32, 4);
    attn_fuse<<<(unsigned)M, 512, 0, stream>>>(vo, fuse);
    gemm_bt_epi<<<128, 256, 0, stream>>>(fuse, owb, vf, output_b, vo + (size_t)7 * M * C,
                                         (int)M, (int)C, (int)C, 8);
    cos_row<<<(unsigned)M, 256, 0, stream>>>(vf, teacher, cosv);
    final_reduce<<<1, 256, 0, stream>>>(cosv, out);
  } else {
    // SMALL-ws fallback: loop j, reuse one xn/wb slab.
    const size_t xn1B = M * D * 2;
    const size_t wb1B = C * D * 2;
    bf16_t* xn1 = (bf16_t*)ws;
    bf16_t* wb1 = (bf16_t*)(ws + xn1B);
    bf16_t* owb = (bf16_t*)(ws + xn1B + wb1B);
    float* vo = (float*)(ws + xn1B + wb1B + owbB);
    bf16_t* fuse = (bf16_t*)(ws + xn1B + wb1B + owbB + voB);
    float* vf = (float*)(ws + xn1B + wb1B + owbB + voB + fuseB);
    float* cosv = (float*)(ws + xn1B + wb1B + owbB + voB + fuseB + vfB);

    cvt_bf16<<<512, 256, 0, stream>>>(output_w, owb, (long)(C * C));
    for (int j = 0; j < 8; ++j) {
      const float* wsrc = (j < 7) ? (norm_w + (size_t)j * C * D) : input_w;
      cvt_bf16<<<2048, 256, 0, stream>>>(wsrc, wb1, (long)(C * D));
      dim3 g1((unsigned)M, 1);
      ln_convert<<<g1, 256, 0, stream>>>(all_features, ln_gamma, ln_beta, xn1, j);
      gemm256<<<32, 512, 0, stream>>>(xn1, wb1, vo, input_b,
                                      (int)M, (int)C, (int)D, j, 32, 4);
    }
    attn_fuse<<<(unsigned)M, 512, 0, stream>>>(vo, fuse);
    gemm_bt_epi<<<128, 256, 0, stream>>>(fuse, owb, vf, output_b, vo + (size_t)7 * M * C,
                                         (int)M, (int)C, (int)C, 8);
    cos_row<<<(unsigned)M, 256, 0, stream>>>(vf, teacher, cosv);
    final_reduce<<<1, 256, 0, stream>>>(cosv, out);
  }
}

// Round 6
// 285.314 us; speedup vs baseline: 1.4452x; 1.0556x over previous
//
#include <hip/hip_runtime.h>
#include <cstdint>
#include <cstring>

#define M_TOK 2048   // BT*S
#define DDIM 4096
#define CDIM 1024
#define LTOT 25

typedef __bf16 bf16_t;
typedef __attribute__((ext_vector_type(8))) __bf16 bf16x8;
typedef __attribute__((ext_vector_type(4))) float f32x4;

__device__ __forceinline__ void gload16(const void* g, void* l) {
  __builtin_amdgcn_global_load_lds(
      (const __attribute__((address_space(1))) unsigned int*)g,
      (__attribute__((address_space(3))) unsigned int*)l, 16, 0, 0);
}

// ---------------- fp32 -> bf16 convert ----------------
__global__ void cvt_bf16(const float* __restrict__ src, bf16_t* __restrict__ dst, long n) {
  long stride = (long)gridDim.x * blockDim.x;
  for (long i = (long)blockIdx.x * blockDim.x + threadIdx.x; i * 8 < n; i += stride) {
    const float4* s4 = (const float4*)(src + i * 8);
    float4 a = s4[0], b = s4[1];
    bf16_t o[8] = {(bf16_t)a.x, (bf16_t)a.y, (bf16_t)a.z, (bf16_t)a.w,
                   (bf16_t)b.x, (bf16_t)b.y, (bf16_t)b.z, (bf16_t)b.w};
    uint4 pk;
    __builtin_memcpy(&pk, o, 16);
    *(uint4*)(dst + i * 8) = pk;
  }
}

// ---------------- LayerNorm + gather + bf16 convert ----------------
// fuse7: when jl==0, also write the raw layer-24 row into slab 7 (fast path).
__global__ __launch_bounds__(256)
void ln_convert(const float* __restrict__ af, const float* __restrict__ gamma,
                const float* __restrict__ beta, bf16_t* __restrict__ xn,
                int jBase, int fuse7)
{
  int m = blockIdx.x;
  int jl = blockIdx.y;
  int j = jBase + jl;
  int layer = (j < 7) ? (24 - 4 * j) : 24;
  const float4* row4 = (const float4*)(af + ((size_t)m * LTOT + layer) * DDIM);
  int tid = threadIdx.x;
  float4 v[4];
  float s = 0.f, ss = 0.f;
#pragma unroll
  for (int i = 0; i < 4; ++i) {
    v[i] = row4[i * 256 + tid];
    s += v[i].x + v[i].y + v[i].z + v[i].w;
    ss += v[i].x * v[i].x + v[i].y * v[i].y + v[i].z * v[i].z + v[i].w * v[i].w;
  }
  int lane = tid & 63, wv = tid >> 6;
#pragma unroll
  for (int off = 32; off; off >>= 1) { s += __shfl_xor(s, off); ss += __shfl_xor(ss, off); }
  __shared__ float red[8];
  if (lane == 0) { red[wv] = s; red[4 + wv] = ss; }
  __syncthreads();
  s = red[0] + red[1] + red[2] + red[3];
  ss = red[4] + red[5] + red[6] + red[7];
  float mu = 0.f, rs = 1.f;
  if (j < 7) {
    mu = s * (1.f / DDIM);
    float var = ss * (1.f / DDIM) - mu * mu;
    rs = rsqrtf(var + 1e-5f);
  }
  // raw copy into slab 7 (fused with jl==0 which reads layer 24)
  if (fuse7 && jl == 0) {
    bf16_t* o7 = xn + ((size_t)7 * M_TOK + m) * DDIM;
#pragma unroll
    for (int i = 0; i < 4; ++i) {
      bf16_t o[4] = {(bf16_t)v[i].x, (bf16_t)v[i].y, (bf16_t)v[i].z, (bf16_t)v[i].w};
      uint2 pk;
      __builtin_memcpy(&pk, o, 8);
      ((uint2*)o7)[i * 256 + tid] = pk;
    }
  }
  bf16_t* orow = xn + ((size_t)jl * M_TOK + m) * DDIM;
  int jw = (j < 7) ? j : 0;
  const float4* g4 = (const float4*)(gamma + (size_t)jw * DDIM);
  const float4* b4 = (const float4*)(beta + (size_t)jw * DDIM);
#pragma unroll
  for (int i = 0; i < 4; ++i) {
    float4 x = v[i];
    float4 ov;
    if (j < 7) {
      float4 g = g4[i * 256 + tid], bb = b4[i * 256 + tid];
      ov.x = (x.x - mu) * rs * g.x + bb.x;
      ov.y = (x.y - mu) * rs * g.y + bb.y;
      ov.z = (x.z - mu) * rs * g.z + bb.z;
      ov.w = (x.w - mu) * rs * g.w + bb.w;
    } else ov = x;
    bf16_t o[4] = {(bf16_t)ov.x, (bf16_t)ov.y, (bf16_t)ov.z, (bf16_t)ov.w};
    uint2 pk;
    __builtin_memcpy(&pk, o, 8);
    ((uint2*)orow)[i * 256 + tid] = pk;
  }
}

// ---------------- 256x256-tile 8-phase batched B^T GEMM, deep-slack ladder -------
// C[jg][m][n] = bf16( sum_k A[jl][m][k] * B[jl][n][k] (+bias) )
// 512 threads = 8 waves (2 wm x 4 wn); per-wave output 128x64. BK=64.
// Staging schedule (slack >= 2.5 phases for every waited load):
//   ph0: B0,B1(t+1)  ph1: B2,B3(t+1)  ph2: A1,A3(t+1)  ph3: A0,A2(t+2)
// Waits: ph1-end vmcnt(6), ph3-end vmcnt(4) (tails: 6/2 at NT-2, 0/none at NT-1).
// Race audit: buf (t+2)&1 regions A0/A2 are free after ph2's 2nd barrier of iter t
// (last reads of tile t's A1/A3 are disjoint chunks; tile-t A0/A2 reads completed
// in ph0). All waited loads are >=2 barriers older than their first read.
__global__ __launch_bounds__(512, 2)
void gemm256(const bf16_t* __restrict__ A, const bf16_t* __restrict__ B,
             bf16_t* __restrict__ Cout, const float* __restrict__ bias,
             int Mm, int Nn, int Kk, int jBase, int tilesPerJ, int tilesN)
{
  __shared__ __align__(16) char smem[131072];  // [0,64K) A bufs, [64K,128K) B bufs
  int nb = gridDim.x;
  int bid = blockIdx.x;
  if ((nb & 7) == 0) { int cpx = nb >> 3; bid = (bid & 7) * cpx + (bid >> 3); }  // XCD swizzle
  int jl = bid / tilesPerJ;
  int t0 = bid % tilesPerJ;
  int bm = t0 / tilesN, bn = t0 % tilesN;
  int jg = jBase + jl;

  const bf16_t* Aj = A + (size_t)jl * Mm * Kk + (size_t)bm * 256 * Kk;
  const bf16_t* Bj = B + (size_t)jl * Nn * Kk + (size_t)bn * 256 * Kk;

  int tid = threadIdx.x;
  int lane = tid & 63, wid = tid >> 6;
  int wm = wid >> 2, wn = wid & 3;
  int wm2 = wm * 2;

  // staging source (per chunk c, tile tt): row = c*64 + wid*8 + (lane>>3),
  // k-slot pre-swizzle gslot = (lane&7)^((lane>>3)&7)
  const bf16_t* Ast = Aj + (size_t)(wid * 8 + (lane >> 3)) * Kk + ((lane & 7) ^ ((lane >> 3) & 7)) * 8;
  const bf16_t* Bst = Bj + (size_t)(wid * 8 + (lane >> 3)) * Kk + ((lane & 7) ^ ((lane >> 3) & 7)) * 8;

  // read addressing: stored slot s of row r holds global k-slot s^(r&7)
  int rb = lane & 15;
  int s0 = (((lane >> 4)) ^ (lane & 7)) * 16;      // k-slice 0 byte offset in 128B row
  int s1 = ((4 | (lane >> 4)) ^ (lane & 7)) * 16;  // k-slice 1

  int NT = Kk >> 6;
  f32x4 acc[8][4] = {};
  bf16x8 Af[4][2], Bf[4][2];

#define STAGEA(c_, tt_)                                                          \
  gload16(Ast + (size_t)(c_) * 64 * Kk + (size_t)(tt_) * 64,                     \
          &smem[(((tt_) & 1) * 32768) + (c_) * 8192 + wid * 1024])
#define STAGEB(c_, tt_)                                                          \
  gload16(Bst + (size_t)(c_) * 64 * Kk + (size_t)(tt_) * 64,                     \
          &smem[65536 + (((tt_) & 1) * 32768) + (c_) * 8192 + wid * 1024])

#define LOADA(buf_, ih_)                                                         \
  { const char* Ac_ = &smem[(buf_) * 32768 + (wm2 + (ih_)) * 8192];              \
    _Pragma("unroll")                                                            \
    for (int ip_ = 0; ip_ < 4; ++ip_) {                                          \
      Af[ip_][0] = *(const bf16x8*)(Ac_ + (ip_ * 16 + rb) * 128 + s0);           \
      Af[ip_][1] = *(const bf16x8*)(Ac_ + (ip_ * 16 + rb) * 128 + s1);           \
    } }

#define LOADB(buf_, jh_)                                                         \
  { const char* Bc_ = &smem[65536 + (buf_) * 32768 + wn * 8192];                 \
    _Pragma("unroll")                                                            \
    for (int jp_ = 0; jp_ < 2; ++jp_) {                                          \
      Bf[(jh_) * 2 + jp_][0] = *(const bf16x8*)(Bc_ + (((jh_) * 2 + jp_) * 16 + rb) * 128 + s0); \
      Bf[(jh_) * 2 + jp_][1] = *(const bf16x8*)(Bc_ + (((jh_) * 2 + jp_) * 16 + rb) * 128 + s1); \
    } }

#define MFMAQ(ih_, jh_)                                                          \
  { __builtin_amdgcn_s_setprio(1);                                               \
    _Pragma("unroll")                                                            \
    for (int ip_ = 0; ip_ < 4; ++ip_)                                            \
      _Pragma("unroll")                                                          \
      for (int jp_ = 0; jp_ < 2; ++jp_)                                          \
        _Pragma("unroll")                                                        \
        for (int k_ = 0; k_ < 2; ++k_)                                           \
          acc[(ih_) * 4 + ip_][(jh_) * 2 + jp_] =                                \
              __builtin_amdgcn_mfma_f32_16x16x32_bf16(                           \
                  Af[ip_][k_], Bf[(jh_) * 2 + jp_][k_],                          \
                  acc[(ih_) * 4 + ip_][(jh_) * 2 + jp_], 0, 0, 0);               \
    __builtin_amdgcn_s_setprio(0); }

#define BAR() asm volatile("s_barrier" ::: "memory")
#define LGKM0() asm volatile("s_waitcnt lgkmcnt(0)" ::: "memory")

  // prologue: tile 0 (8 loads) + A0,A2 of tile 1 (ph3-of-iter(-1) role) = 10
  STAGEB(0, 0); STAGEB(1, 0); STAGEB(2, 0); STAGEB(3, 0);
  STAGEA(0, 0); STAGEA(2, 0); STAGEA(1, 0); STAGEA(3, 0);
  if (NT > 1) { STAGEA(0, 1); STAGEA(2, 1); }
  asm volatile("s_waitcnt vmcnt(4)" ::: "memory");  // tile-0 B*,A0,A2 landed
  BAR();

#pragma unroll 1
  for (int t = 0; t < NT; ++t) {
    int buf = t & 1;
    // ---- phase 0: quadrant (0,0); stage B0,B1(t+1) ----
    LOADA(buf, 0);
    LOADB(buf, 0);
    if (t + 1 < NT) { STAGEB(0, t + 1); STAGEB(1, t + 1); }
    BAR(); LGKM0();
    MFMAQ(0, 0);
    BAR();
    // ---- phase 1: quadrant (0,1); stage B2,B3(t+1); wait for A1,A3(t) ----
    LOADB(buf, 1);
    if (t + 1 < NT) { STAGEB(2, t + 1); STAGEB(3, t + 1); }
    BAR(); LGKM0();
    MFMAQ(0, 1);
    if (t + 1 < NT) asm volatile("s_waitcnt vmcnt(6)" ::: "memory");
    else            asm volatile("s_waitcnt vmcnt(0)" ::: "memory");
    BAR();
    // ---- phase 2: quadrant (1,0); stage A1,A3(t+1) ----
    LOADA(buf, 1);
    if (t + 1 < NT) { STAGEA(1, t + 1); STAGEA(3, t + 1); }
    BAR(); LGKM0();
    MFMAQ(1, 0);
    BAR();
    // ---- phase 3: quadrant (1,1); stage A0,A2(t+2); wait for tile t+1 B*,A0,A2 ----
    if (t + 2 < NT) { STAGEA(0, t + 2); STAGEA(2, t + 2); }
    BAR(); LGKM0();
    MFMAQ(1, 1);
    if (t + 2 < NT)      asm volatile("s_waitcnt vmcnt(4)" ::: "memory");
    else if (t + 1 < NT) asm volatile("s_waitcnt vmcnt(2)" ::: "memory");
    BAR();
  }
#undef STAGEA
#undef STAGEB
#undef LOADA
#undef LOADB
#undef MFMAQ
#undef BAR
#undef LGKM0

  int rowBase = bm * 256 + wm * 128 + (lane >> 4) * 4;
  int colBase = bn * 256 + wn * 64 + (lane & 15);
  bf16_t* Cj = Cout + (size_t)jg * Mm * Nn;
#pragma unroll
  for (int i = 0; i < 8; ++i) {
#pragma unroll
    for (int j = 0; j < 4; ++j) {
      int gn = colBase + j * 16;
      float bv = (jg == 7) ? bias[gn] : 0.f;
#pragma unroll
      for (int r = 0; r < 4; ++r) {
        int gm = rowBase + i * 16 + r;
        Cj[(size_t)gm * Nn + gn] = (bf16_t)(acc[i][j][r] + bv);
      }
    }
  }
}

// ---------------- 128x128-tile GEMM for the output projection ----------------
// C[m][n] = sum_k A[m][k]*B[n][k] + bias[n] + vin[m][n]   (vin bf16)
__global__ __launch_bounds__(256)
void gemm_bt_epi(const bf16_t* __restrict__ A, const bf16_t* __restrict__ B,
                 float* __restrict__ Cout, const float* __restrict__ bias,
                 const bf16_t* __restrict__ vin, int Mm, int Nn, int Kk, int tilesN)
{
  __shared__ bf16_t As[128 * 64];
  __shared__ bf16_t Bs[128 * 64];
  int bid = blockIdx.x;
  int bm = bid / tilesN, bn = bid % tilesN;
  const bf16_t* Aj = A + (size_t)bm * 128 * Kk;
  const bf16_t* Bj = B + (size_t)bn * 128 * Kk;

  int tid = threadIdx.x;
  int lane = tid & 63, wv = tid >> 6;
  int wm = wv >> 1, wn = wv & 1;

  f32x4 acc[4][4] = {};

  int srow = wv * 32 + (lane >> 3);
  int scol = (lane & 7) * 8;
  const bf16_t* Ag = Aj + (size_t)srow * Kk + scol;
  const bf16_t* Bg = Bj + (size_t)srow * Kk + scol;

  for (int kt = 0; kt < Kk; kt += 64) {
#pragma unroll
    for (int c = 0; c < 4; ++c) {
      gload16(Ag + kt + (size_t)(c * 8) * Kk, &As[(wv * 32 + c * 8) * 64]);
      gload16(Bg + kt + (size_t)(c * 8) * Kk, &Bs[(wv * 32 + c * 8) * 64]);
    }
    __syncthreads();
#pragma unroll
    for (int ks = 0; ks < 2; ++ks) {
      int ko = ks * 32 + (lane >> 4) * 8;
      bf16x8 af[4], bfr[4];
#pragma unroll
      for (int i = 0; i < 4; ++i) {
        af[i] = *(const bf16x8*)&As[(wm * 64 + i * 16 + (lane & 15)) * 64 + ko];
        bfr[i] = *(const bf16x8*)&Bs[(wn * 64 + i * 16 + (lane & 15)) * 64 + ko];
      }
#pragma unroll
      for (int i = 0; i < 4; ++i)
#pragma unroll
        for (int j2 = 0; j2 < 4; ++j2)
          acc[i][j2] = __builtin_amdgcn_mfma_f32_16x16x32_bf16(af[i], bfr[j2], acc[i][j2], 0, 0, 0);
    }
    __syncthreads();
  }

  int rowBase = bm * 128 + wm * 64 + (lane >> 4) * 4;
  int colBase = bn * 128 + wn * 64 + (lane & 15);
#pragma unroll
  for (int i = 0; i < 4; ++i) {
#pragma unroll
    for (int j2 = 0; j2 < 4; ++j2) {
      int gn = colBase + j2 * 16;
      float bv = bias[gn];
#pragma unroll
      for (int r = 0; r < 4; ++r) {
        int gm = rowBase + i * 16 + r;
        Cout[(size_t)gm * Nn + gn] = acc[i][j2][r] + bv + (float)vin[(size_t)gm * Nn + gn];
      }
    }
  }
}

// ---------------- attention over 6 kv slabs (vo bf16) ----------------
__global__ __launch_bounds__(512)
void attn_fuse(const bf16_t* __restrict__ vo, bf16_t* __restrict__ fuse)
{
  int m = blockIdx.x;
  int h = threadIdx.x >> 6;
  int lane = threadIdx.x & 63;
  const size_t slab = (size_t)M_TOK * CDIM;
  const bf16_t* base = vo + (size_t)m * CDIM + h * 128;
  float q0 = (float)base[lane], q1 = (float)base[lane + 64];
  float kv0[6], kv1[6], sc[6];
#pragma unroll
  for (int k = 0; k < 6; ++k) {
    const bf16_t* kb = base + (size_t)(k + 1) * slab;
    kv0[k] = (float)kb[lane]; kv1[k] = (float)kb[lane + 64];
    sc[k] = q0 * kv0[k] + q1 * kv1[k];
  }
#pragma unroll
  for (int k = 0; k < 6; ++k) {
#pragma unroll
    for (int off = 32; off; off >>= 1) sc[k] += __shfl_xor(sc[k], off);
    sc[k] *= 0.03125f;  // C^-0.5
  }
  float mx = sc[0];
#pragma unroll
  for (int k = 1; k < 6; ++k) mx = fmaxf(mx, sc[k]);
  float e[6], se = 0.f;
#pragma unroll
  for (int k = 0; k < 6; ++k) { e[k] = expf(sc[k] - mx); se += e[k]; }
  float inv = 1.f / se;
  float f0 = 0.f, f1 = 0.f;
#pragma unroll
  for (int k = 0; k < 6; ++k) { float w = e[k] * inv; f0 += w * kv0[k]; f1 += w * kv1[k]; }
  bf16_t* o = fuse + (size_t)m * CDIM + h * 128;
  o[lane] = (bf16_t)f0;
  o[lane + 64] = (bf16_t)f1;
}

// ---------------- cosine per row ----------------
__global__ __launch_bounds__(256)
void cos_row(const float* __restrict__ vf, const float* __restrict__ teacher, float* __restrict__ cosv)
{
  int m = blockIdx.x;
  int tid = threadIdx.x;
  float4 a = ((const float4*)(vf + (size_t)m * CDIM))[tid];
  float4 b = ((const float4*)(teacher + (size_t)m * CDIM))[tid];
  float dot = a.x * b.x + a.y * b.y + a.z * b.z + a.w * b.w;
  float na = a.x * a.x + a.y * a.y + a.z * a.z + a.w * a.w;
  float nb = b.x * b.x + b.y * b.y + b.z * b.z + b.w * b.w;
  int lane = tid & 63, wv = tid >> 6;
#pragma unroll
  for (int off = 32; off; off >>= 1) {
    dot += __shfl_xor(dot, off); na += __shfl_xor(na, off); nb += __shfl_xor(nb, off);
  }
  __shared__ float red[12];
  if (lane == 0) { red[wv] = dot; red[4 + wv] = na; red[8 + wv] = nb; }
  __syncthreads();
  if (tid == 0) {
    float d = red[0] + red[1] + red[2] + red[3];
    float x = red[4] + red[5] + red[6] + red[7];
    float y = red[8] + red[9] + red[10] + red[11];
    float den = fmaxf(sqrtf(x), 1e-8f) * fmaxf(sqrtf(y), 1e-8f);
    cosv[m] = d / den;
  }
}

__global__ __launch_bounds__(256)
void final_reduce(const float* __restrict__ cosv, float* __restrict__ out)
{
  int tid = threadIdx.x;
  float s = 0.f;
  for (int i = tid; i < M_TOK; i += 256) s += cosv[i];
  int lane = tid & 63, wv = tid >> 6;
#pragma unroll
  for (int off = 32; off; off >>= 1) s += __shfl_xor(s, off);
  __shared__ float red[4];
  if (lane == 0) red[wv] = s;
  __syncthreads();
  if (tid == 0) out[0] = 1.f - (red[0] + red[1] + red[2] + red[3]) * (1.f / M_TOK);
}

extern "C" void kernel_launch(void* const* d_in, const int* in_sizes, int n_in,
                              void* d_out, int out_size, void* d_ws, size_t ws_size,
                              hipStream_t stream)
{
  (void)in_sizes; (void)n_in; (void)out_size;
  const float* all_features = (const float*)d_in[0];
  const float* teacher = (const float*)d_in[1];
  const float* ln_gamma = (const float*)d_in[2];
  const float* ln_beta = (const float*)d_in[3];
  const float* norm_w = (const float*)d_in[4];
  const float* input_w = (const float*)d_in[5];
  const float* input_b = (const float*)d_in[6];
  const float* output_w = (const float*)d_in[7];
  const float* output_b = (const float*)d_in[8];
  float* out = (float*)d_out;
  char* ws = (char*)d_ws;

  const size_t M = M_TOK, D = DDIM, C = CDIM;
  const size_t xnB = 8 * M * D * 2;      // 134 MB
  const size_t wbB = 8 * C * D * 2;      // 67 MB
  const size_t owbB = C * C * 2;         // 2 MB
  const size_t voB = 8 * M * C * 2;      // 33.5 MB (bf16; slab7 = vin)
  const size_t fuseB = M * C * 2;
  const size_t vfB = M * C * 4;
  const size_t cosB = M * 4;
  const size_t fastTotal = xnB + wbB + owbB + voB + fuseB + vfB + cosB;

  if (ws_size >= fastTotal) {
    bf16_t* xn = (bf16_t*)ws;
    bf16_t* wb = (bf16_t*)(ws + xnB);
    bf16_t* owb = (bf16_t*)(ws + xnB + wbB);
    bf16_t* vo = (bf16_t*)(ws + xnB + wbB + owbB);
    bf16_t* fuse = (bf16_t*)(ws + xnB + wbB + owbB + voB);
    float* vf = (float*)(ws + xnB + wbB + owbB + voB + fuseB);
    float* cosv = (float*)(ws + xnB + wbB + owbB + voB + fuseB + vfB);

    cvt_bf16<<<4096, 256, 0, stream>>>(norm_w, wb, (long)7 * C * D);
    cvt_bf16<<<2048, 256, 0, stream>>>(input_w, wb + (size_t)7 * C * D, (long)(C * D));
    cvt_bf16<<<512, 256, 0, stream>>>(output_w, owb, (long)(C * C));
    dim3 g1((unsigned)M, 7);
    ln_convert<<<g1, 256, 0, stream>>>(all_features, ln_gamma, ln_beta, xn, 0, 1);
    gemm256<<<256, 512, 0, stream>>>(xn, wb, vo, input_b,
                                     (int)M, (int)C, (int)D, 0, 32, 4);
    attn_fuse<<<(unsigned)M, 512, 0, stream>>>(vo, fuse);
    gemm_bt_epi<<<128, 256, 0, stream>>>(fuse, owb, vf, output_b, vo + (size_t)7 * M * C,
                                         (int)M, (int)C, (int)C, 8);
    cos_row<<<(unsigned)M, 256, 0, stream>>>(vf, teacher, cosv);
    final_reduce<<<1, 256, 0, stream>>>(cosv, out);
  } else {
    // SMALL-ws fallback: loop j, reuse one xn/wb slab.
    const size_t xn1B = M * D * 2;
    const size_t wb1B = C * D * 2;
    bf16_t* xn1 = (bf16_t*)ws;
    bf16_t* wb1 = (bf16_t*)(ws + xn1B);
    bf16_t* owb = (bf16_t*)(ws + xn1B + wb1B);
    bf16_t* vo = (bf16_t*)(ws + xn1B + wb1B + owbB);
    bf16_t* fuse = (bf16_t*)(ws + xn1B + wb1B + owbB + voB);
    float* vf = (float*)(ws + xn1B + wb1B + owbB + voB + fuseB);
    float* cosv = (float*)(ws + xn1B + wb1B + owbB + voB + fuseB + vfB);

    cvt_bf16<<<512, 256, 0, stream>>>(output_w, owb, (long)(C * C));
    for (int j = 0; j < 8; ++j) {
      const float* wsrc = (j < 7) ? (norm_w + (size_t)j * C * D) : input_w;
      cvt_bf16<<<2048, 256, 0, stream>>>(wsrc, wb1, (long)(C * D));
      dim3 g1((unsigned)M, 1);
      ln_convert<<<g1, 256, 0, stream>>>(all_features, ln_gamma, ln_beta, xn1, j, 0);
      gemm256<<<32, 512, 0, stream>>>(xn1, wb1, vo, input_b,
                                      (int)M, (int)C, (int)D, j, 32, 4);
    }
    attn_fuse<<<(unsigned)M, 512, 0, stream>>>(vo, fuse);
    gemm_bt_epi<<<128, 256, 0, stream>>>(fuse, owb, vf, output_b, vo + (size_t)7 * M * C,
                                         (int)M, (int)C, (int)C, 8);
    cos_row<<<(unsigned)M, 256, 0, stream>>>(vf, teacher, cosv);
    final_reduce<<<1, 256, 0, stream>>>(cosv, out);
  }
}